// Round 13
// baseline (193.331 us; speedup 1.0000x reference)
//
#include <hip/hip_runtime.h>
#include <hip/hip_fp16.h>

#define H 256
#define W 512
#define HW (H*W)
#define NPIXF 524288.0f
#define SPAN 11
#define KK 23
#define NBINS (KK*KK)   // 529

#define LOG2E 1.4426950408889634f
#define CEXP  (-0.7213475204444817f)   // -0.5*log2(e)
#define CIND  (CEXP/36.0f)             // 1/SIG_XY^2
// sqrt(|CEXP|*100) and sqrt(|CEXP|*25): fold rgb/depth sigma scaling into staged f16 data
#define KRGB  8.4932180f
#define KDEP  4.2466090f

// tile geometry: center 32 cols x 32 rows per block, halo +11 rows below,
// ONE-SIDED 11-col halo (db-split makes the other side unnecessary)
#define TX 32
#define TYR 32
#define TROWS 43          // TYR + 11
#define TCOLS 43          // TX + 11 (one-sided halo)
#define TPIX (TROWS*TCOLS) // 1849

#define NTILE 512         // 32x32-center tiles: 4 batches x 8 rowtiles x 16 coltiles
#define NCRF (NTILE*4)    // 4 blocks per tile (db quarters)
#define NSTAT 44

typedef _Float16 h2 __attribute__((ext_vector_type(2)));

struct alignas(16) PixV { h2 rg, bd, y01, y2m; };   // 16 B staged pixel (rgb,d pre-scaled)

__device__ __forceinline__ h2 pack2(float a, float b) {
  h2 r; r.x = (_Float16)a; r.y = (_Float16)b; return r;
}

// 64-lane sum on the VALU pipe (DPP). Total lands in lane 63.
__device__ __forceinline__ float dpp_sum(float x) {
  x += __int_as_float(__builtin_amdgcn_update_dpp(0, __float_as_int(x), 0x111, 0xf, 0xf, true)); // row_shr:1
  x += __int_as_float(__builtin_amdgcn_update_dpp(0, __float_as_int(x), 0x112, 0xf, 0xf, true)); // row_shr:2
  x += __int_as_float(__builtin_amdgcn_update_dpp(0, __float_as_int(x), 0x114, 0xf, 0xf, true)); // row_shr:4
  x += __int_as_float(__builtin_amdgcn_update_dpp(0, __float_as_int(x), 0x118, 0xf, 0xf, true)); // row_shr:8
  x += __int_as_float(__builtin_amdgcn_update_dpp(0, __float_as_int(x), 0x142, 0xa, 0xf, true)); // row_bcast:15
  x += __int_as_float(__builtin_amdgcn_update_dpp(0, __float_as_int(x), 0x143, 0xc, 0xf, true)); // row_bcast:31
  return x;
}

__device__ __forceinline__ float wave_sum(float x) {
  #pragma unroll
  for (int s = 1; s < 64; s <<= 1) x += __shfl_xor(x, s, 64);
  return x;
}

// pair compatibility: kv(a1,a2) * (1 - <yC, yN>), all f16-packed inputs
__device__ __forceinline__ float paircc(const PixV& C, const PixV& N,
                                        h2 nc01, h2 nc2z, float lind) {
  h2 drg = N.rg - C.rg;            // v_pk_add_f16 (neg)
  h2 dbd = N.bd - C.bd;
  float dbf = (float)dbd.x;
  float ddf = (float)dbd.y;
#if __has_builtin(__builtin_amdgcn_fdot2)
  float q  = __builtin_amdgcn_fdot2(drg, drg, dbf*dbf, false);   // dr^2+dg^2+db^2 (scaled)
  float a1 = lind - q;
  float w1 = __builtin_amdgcn_fdot2(N.y01, nc01, 1.0f, false);   // 1 - y0Y0 - y1Y1
  float w  = __builtin_amdgcn_fdot2(N.y2m, nc2z, w1, false);     // ... - y2Y2 (m lane masked by 0)
#else
  float dr = (float)drg.x, dg = (float)drg.y;
  float a1 = fmaf(-dr, dr, fmaf(-dg, dg, fmaf(-dbf, dbf, lind)));
  float ny0 = (float)N.y01.x, ny1 = (float)N.y01.y, ny2 = (float)N.y2m.x;
  float cy0 = (float)C.y01.x, cy1 = (float)C.y01.y, cy2 = (float)C.y2m.x;
  float w  = fmaf(-ny0, cy0, fmaf(-ny1, cy1, fmaf(-ny2, cy2, 1.0f)));
  (void)nc01; (void)nc2z;
#endif
  float a2 = -(ddf*ddf);
  float kv = __builtin_amdgcn_exp2f(a1) + __builtin_amdgcn_exp2f(a2);
  return kv * w;
}

// ---------------- crf_kernel: f16 LDS tile (one-sided halo), 4 center rows/thread,
//                  db-quartered blocks, DPP reductions, fused softmax/CE + stats blocks ----------------
__global__ __launch_bounds__(256, 5) void crf_kernel(
    const float* __restrict__ logit, const int* __restrict__ target,
    const float* __restrict__ image, const float* __restrict__ depth,
    const float* __restrict__ dst,
    float* __restrict__ g_bins, float* __restrict__ g_ce,
    float* __restrict__ rowBand, float* __restrict__ colBand) {
  __shared__ PixV  tile[TPIX];
  __shared__ float binsS[NBINS];
  __shared__ float redS[12];

  int tx = threadIdx.x;
  int bid = blockIdx.x;
  int lane = tx & 63;

  if (bid >= NCRF) {           // ---- stats path: margin band sums of dst ----
    int k = bid - NCRF;
    float s = 0.f;
    if (k < 22) {
      int row = (k < 11) ? k : (234 + k);
      for (int t = tx; t < 2048; t += 256) {
        int b = t >> 9, j = t & 511;
        s += dst[(size_t)b*HW + row*W + j];
      }
    } else {
      int kc = k - 22;
      int col = (kc < 11) ? kc : (490 + kc);
      for (int t = tx; t < 1024; t += 256) {
        int b = t >> 8, i = t & 255;
        s += dst[(size_t)b*HW + i*W + col];
      }
    }
    s = wave_sum(s);
    if ((tx & 63) == 0) redS[tx >> 6] = s;
    __syncthreads();
    if (tx == 0) {
      float tot = redS[0] + redS[1] + redS[2] + redS[3];
      if (k < 22) rowBand[k] = tot; else colBand[k - 22] = tot;
    }
    return;
  }

  int tileId  = bid >> 2;      // 512 tiles
  int quarter = bid & 3;       // db quarters: {-11..-6}, {-5..-1}, {+1..+6}, {+7..+11}
  int bz = tileId >> 7;        // 128 tiles per batch (8 row-tiles x 16 col-tiles)
  int rem = tileId & 127;
  int i0 = (rem >> 4) * TYR;
  int j0 = (rem & 15) * TX;
  int co = (quarter < 2) ? 11 : 0;   // center col offset inside tile (halo side)
  int cbase = j0 - co;               // global col of tile col 0
  int biLo  = quarter*6 - ((quarter > 1) ? 1 : 0);   // 0, 6, 11, 17
  int biCnt = 6 - (quarter & 1);                      // 6, 5, 6, 5

  const float* lg0 = logit + (size_t)bz*3*HW;
  const float* lg1 = lg0 + HW;
  const float* lg2 = lg0 + 2*HW;
  const float* im0 = image + (size_t)bz*3*HW;
  const float* im1 = im0 + HW;
  const float* im2 = im0 + 2*HW;
  const float* dep = depth + (size_t)bz*HW;
  const float* dsb = dst   + (size_t)bz*HW;
  const int*   tgb = target + (size_t)bz*HW;

  for (int s = tx; s < NBINS; s += 256) binsS[s] = 0.f;

  // --- staging: global -> LDS (f16 pack, rgb/d pre-scaled) with fused softmax;
  //     CE + sum(m) only on quarter 0 (avoid double count) ---
  float v0 = 0.f, v1 = 0.f, v2 = 0.f;
  for (int s = tx; s < TPIX; s += 256) {
    int r = s / TCOLS, c = s - r*TCOLS;
    int gi = i0 + r, gj = cbase + c;
    PixV ph;
    if (gi < H && (unsigned)gj < (unsigned)W) {
      int q = gi*W + gj;
      float l0 = lg0[q], l1 = lg1[q], l2 = lg2[q];
      float mx = fmaxf(l0, fmaxf(l1, l2));
      float e0 = __builtin_amdgcn_exp2f((l0-mx)*LOG2E);
      float e1 = __builtin_amdgcn_exp2f((l1-mx)*LOG2E);
      float e2 = __builtin_amdgcn_exp2f((l2-mx)*LOG2E);
      float S = e0+e1+e2;
      float inv = 1.0f/S;
      float m = dsb[q];
      ph.rg  = pack2(im0[q]*KRGB, im1[q]*KRGB);
      ph.bd  = pack2(im2[q]*KRGB, dep[q]*KDEP);
      ph.y01 = pack2(e0*inv, e1*inv);
      ph.y2m = pack2(e2*inv, m);
      if (quarter == 0 && r < TYR && c >= co && c < co+TX) {   // center pixel, once per tile
        int t = tgb[q];
        float lt = (t==0) ? l0 : ((t==1) ? l1 : l2);
        float lce = mx + __logf(S) - lt;
        float t0 = lce * m;
        v0 += t0;
        v1 += lce - t0;
        v2 += m;
      }
    } else {
      ph.rg = ph.bd = pack2(1e30f, 1e30f);   // +inf sentinel -> kernel = 0
      ph.y01 = ph.y2m = pack2(0.f, 0.f);     // m = 0
    }
    tile[s] = ph;
  }
  __syncthreads();

  // --- main pair loop: thread owns 4 center rows; this block's 5-6 db offsets; both bins.
  //     One ds_read + one DPP-reduce pair per iteration covers 4 pixel-pairs. ---
  int txc = tx & 31, ty = tx >> 5;
  int crow = ty*4;
  int cidx = crow*TCOLS + txc + co;
  PixV c0 = tile[cidx];
  PixV c1 = tile[cidx +   TCOLS];
  PixV c2 = tile[cidx + 2*TCOLS];
  PixV c3 = tile[cidx + 3*TCOLS];
  h2 nc01_0 = -c0.y01, nc01_1 = -c1.y01, nc01_2 = -c2.y01, nc01_3 = -c3.y01;
  h2 nc2z_0; nc2z_0.x = -c0.y2m.x; nc2z_0.y = (_Float16)0.f;
  h2 nc2z_1; nc2z_1.x = -c1.y2m.x; nc2z_1.y = (_Float16)0.f;
  h2 nc2z_2; nc2z_2.x = -c2.y2m.x; nc2z_2.y = (_Float16)0.f;
  h2 nc2z_3; nc2z_3.x = -c3.y2m.x; nc2z_3.y = (_Float16)0.f;
  float cm0 = (float)c0.y2m.y;
  float cm1 = (float)c1.y2m.y;
  float cm2 = (float)c2.y2m.y;
  float cm3 = (float)c3.y2m.y;

  #pragma unroll 1
  for (int ib = 0; ib < biCnt; ++ib) {
    int bi = biLo + ib;
    int db = bi - ((bi < 11) ? 11 : 10);   // quarter's db range
    int nb = cidx + db;
    float lb = CIND * (float)(db*db);
    int bb = SPAN*KK + (db + SPAN);        // bin base; idx(+a,+db) = bb + a*KK, idx(-a,-db) = 528 - that
    // window: at iteration a, w0..w3 = rows crow+a .. crow+a+3 (w_k pairs with center k)
    PixV w0 = tile[nb +   TCOLS];
    PixV w1 = tile[nb + 2*TCOLS];
    PixV w2 = tile[nb + 3*TCOLS];
    float m0 = (float)w0.y2m.y;
    float m1 = (float)w1.y2m.y;
    float m2 = (float)w2.y2m.y;
    #pragma unroll
    for (int a = 1; a <= 11; ++a) {
      PixV w3 = tile[nb + (a+3)*TCOLS];
      float m3 = (float)w3.y2m.y;
      float lind = fmaf((float)(a*a), CIND, lb);   // a const -> folds to add
      float cc0 = paircc(c0, w0, nc01_0, nc2z_0, lind);
      float cc1 = paircc(c1, w1, nc01_1, nc2z_1, lind);
      float cc2 = paircc(c2, w2, nc01_2, nc2z_2, lind);
      float cc3 = paircc(c3, w3, nc01_3, nc2z_3, lind);
      float nd = fmaf(cc3, cm3, fmaf(cc2, cm2, fmaf(cc1, cm1, cc0*cm0)));  // bin(+a,+db), center m
      float nr = fmaf(cc3, m3,  fmaf(cc2, m2,  fmaf(cc1, m1,  cc0*m0)));  // bin(-a,-db), neighbor m
      nd = dpp_sum(nd);
      nr = dpp_sum(nr);
      if (lane == 63) {
        int id = bb + a*KK;
        atomicAdd(&binsS[id], nd);
        atomicAdd(&binsS[528 - id], nr);
      }
      w0 = w1; w1 = w2; w2 = w3;
      m0 = m1; m1 = m2; m2 = m3;
    }
  }
  __syncthreads();

  // --- flush bins (only this quarter's bins are nonzero) + CE (quarter 0) ---
  for (int s = tx; s < NBINS; s += 256) {
    float v = binsS[s];
    if (v != 0.f) unsafeAtomicAdd(&g_bins[s], v);
  }
  if (quarter == 0) {
    v0 = dpp_sum(v0); v1 = dpp_sum(v1); v2 = dpp_sum(v2);
    int wv = tx >> 6;
    if (lane == 63) { redS[wv] = v0; redS[4+wv] = v1; redS[8+wv] = v2; }
    __syncthreads();
    if (tx == 0) {
      unsafeAtomicAdd(&g_ce[0], redS[0]+redS[1]+redS[2]+redS[3]);
      unsafeAtomicAdd(&g_ce[1], redS[4]+redS[5]+redS[6]+redS[7]);
      unsafeAtomicAdd(&g_ce[2], redS[8]+redS[9]+redS[10]+redS[11]);
    }
  }
}

// ---------------- fin_kernel: analytic denominators via 2D prefix sum (inclusion-exclusion) ----------------
__global__ __launch_bounds__(256) void fin_kernel(const float* __restrict__ g_bins,
                                                  const float* __restrict__ g_ce,
                                                  const float* __restrict__ rowBand,
                                                  const float* __restrict__ colBand,
                                                  const float* __restrict__ dst,
                                                  float* __restrict__ out) {
  __shared__ float corner[22][22];
  __shared__ float rowp[22][23];     // exclusive row prefixes of corner
  __shared__ float P[23][23];        // exclusive 2D prefix: P[i][j] = sum_{r<i,c<j} corner[r][c]
  __shared__ float rb[22], cb[22];
  __shared__ float TopP[12], BotS[12], LeftP[12], RightS[12];
  __shared__ float red[4];
  int tx = threadIdx.x;
  if (tx < 22) { rb[tx] = rowBand[tx]; cb[tx] = colBand[tx]; }
  for (int t = tx; t < 484; t += 256) {
    int ri = t / 22, ci = t - ri*22;
    int row = (ri < 11) ? ri : (234 + ri);
    int col = (ci < 11) ? ci : (490 + ci);
    float s = 0.f;
    #pragma unroll
    for (int b = 0; b < 4; ++b) s += dst[(size_t)b*HW + row*W + col];
    corner[ri][ci] = s;
  }
  __syncthreads();

  if (tx < 22) {
    float p = 0.f; rowp[tx][0] = 0.f;
    for (int j = 0; j < 22; ++j) { p += corner[tx][j]; rowp[tx][j+1] = p; }
  }
  else if (tx == 32) { float p=0.f; TopP[0]=0.f;   for (int k=1;k<12;++k){ p += rb[k-1];  TopP[k]=p; } }
  else if (tx == 33) { float p=0.f; BotS[0]=0.f;   for (int k=1;k<12;++k){ p += rb[22-k]; BotS[k]=p; } }
  else if (tx == 34) { float p=0.f; LeftP[0]=0.f;  for (int k=1;k<12;++k){ p += cb[k-1];  LeftP[k]=p; } }
  else if (tx == 35) { float p=0.f; RightS[0]=0.f; for (int k=1;k<12;++k){ p += cb[22-k]; RightS[k]=p; } }
  __syncthreads();

  if (tx < 23) {
    float p = 0.f; P[0][tx] = 0.f;
    for (int i = 0; i < 22; ++i) { p += rowp[i][tx]; P[i+1][tx] = p; }
  }
  __syncthreads();

  float S = g_ce[2];   // sum of dst over everything
  float esum = 0.f;
  for (int od = tx; od < NBINS; od += 256) {
    int dxp = od / KK, dyp = od - dxp*KK;
    int dx = dxp - SPAN, dy = dyp - SPAN;
    if (dx != 0 && dy != 0) {
      int ax = (dx < 0) ? -dx : 0;
      int bx = (dx > 0) ?  dx : 0;
      int ay = (dy < 0) ? -dy : 0;
      int by = (dy > 0) ?  dy : 0;
      float TLv = P[ax][ay];
      float TRv = P[ax][22] - P[ax][22-by];
      float BLv = P[22][ay] - P[22-bx][ay];
      float BRv = P[22][22] - P[22-bx][22] - P[22][22-by] + P[22-bx][22-by];
      float den = S - TopP[ax] - BotS[bx] - LeftP[ay] - RightS[by]
                + TLv + TRv + BLv + BRv;
      esum += g_bins[od] / den;
    }
  }
  esum = wave_sum(esum);
  int lane = tx & 63, wv = tx >> 6;
  if (lane == 0) red[wv] = esum;
  __syncthreads();
  if (tx == 0) {
    float E = (red[0]+red[1]+red[2]+red[3]) / 529.0f;
    float count = S / NPIXF;
    float l1 = g_ce[0] / NPIXF;
    float l2 = g_ce[1] / NPIXF;
    out[0] = l1*(1.0f - count) + l2*count;
    out[1] = E;
  }
}

extern "C" void kernel_launch(void* const* d_in, const int* in_sizes, int n_in,
                              void* d_out, int out_size, void* d_ws, size_t ws_size,
                              hipStream_t stream) {
  const float* logit  = (const float*)d_in[0];
  const int*   target = (const int*)  d_in[1];
  const float* image  = (const float*)d_in[2];
  const float* depth  = (const float*)d_in[3];
  const float* dstm   = (const float*)d_in[4];
  float* out = (float*)d_out;

  float* ws      = (float*)d_ws;
  float* g_bins  = ws;             // 529
  float* g_ce    = ws + NBINS;     // 3  (sum lce*m, sum lce*(1-m), sum m)
  float* rowBand = ws + 532;       // 22
  float* colBand = ws + 554;       // 22

  hipMemsetAsync(ws, 0, 532*sizeof(float), stream);
  crf_kernel<<<NCRF + NSTAT, 256, 0, stream>>>(logit, target, image, depth, dstm,
                                               g_bins, g_ce, rowBand, colBand);
  fin_kernel<<<1, 256, 0, stream>>>(g_bins, g_ce, rowBand, colBand, dstm, out);
}

// Round 14
// 174.112 us; speedup vs baseline: 1.1104x; 1.1104x over previous
//
#include <hip/hip_runtime.h>
#include <hip/hip_fp16.h>

#define H 256
#define W 512
#define HW (H*W)
#define NPIXF 524288.0f
#define SPAN 11
#define KK 23
#define NBINS (KK*KK)   // 529

#define LOG2E 1.4426950408889634f
#define CEXP  (-0.7213475204444817f)   // -0.5*log2(e)
#define CIND  (CEXP/36.0f)             // 1/SIG_XY^2
// sqrt(|CEXP|*100) and sqrt(|CEXP|*25): fold rgb/depth sigma scaling into staged f16 data
#define KRGB  8.4932180f
#define KDEP  4.2466090f

// tile geometry: center 32 cols x 32 rows per block, halo +11 rows below,
// ONE-SIDED 11-col halo (db-split makes the other side unnecessary)
#define TX 32
#define TYR 32
#define TROWS 43          // TYR + 11
#define TCOLS 43          // TX + 11 (one-sided halo)
#define TPIX (TROWS*TCOLS) // 1849

#define NTILE 512         // 32x32-center tiles: 4 batches x 8 rowtiles x 16 coltiles
#define NCRF (NTILE*2)    // 2 blocks per tile (db<0 half, db>0 half)
#define NSTAT 44

typedef _Float16 h2 __attribute__((ext_vector_type(2)));

struct alignas(16) PixV { h2 rg, bd, y01, y2m; };   // 16 B staged pixel (rgb,d pre-scaled)

__device__ __forceinline__ h2 pack2(float a, float b) {
  h2 r; r.x = (_Float16)a; r.y = (_Float16)b; return r;
}

// 64-lane sum on the VALU pipe (DPP). Total lands in lane 63.
__device__ __forceinline__ float dpp_sum(float x) {
  x += __int_as_float(__builtin_amdgcn_update_dpp(0, __float_as_int(x), 0x111, 0xf, 0xf, true)); // row_shr:1
  x += __int_as_float(__builtin_amdgcn_update_dpp(0, __float_as_int(x), 0x112, 0xf, 0xf, true)); // row_shr:2
  x += __int_as_float(__builtin_amdgcn_update_dpp(0, __float_as_int(x), 0x114, 0xf, 0xf, true)); // row_shr:4
  x += __int_as_float(__builtin_amdgcn_update_dpp(0, __float_as_int(x), 0x118, 0xf, 0xf, true)); // row_shr:8
  x += __int_as_float(__builtin_amdgcn_update_dpp(0, __float_as_int(x), 0x142, 0xa, 0xf, true)); // row_bcast:15
  x += __int_as_float(__builtin_amdgcn_update_dpp(0, __float_as_int(x), 0x143, 0xc, 0xf, true)); // row_bcast:31
  return x;
}

__device__ __forceinline__ float wave_sum(float x) {
  #pragma unroll
  for (int s = 1; s < 64; s <<= 1) x += __shfl_xor(x, s, 64);
  return x;
}

// pair compatibility: kv(a1,a2) * (1 - <yC, yN>), all f16-packed inputs.
// Squares of the (b,d) pair computed with one v_pk_mul_f16; exp2 folds the negate.
__device__ __forceinline__ float paircc(const PixV& C, const PixV& N,
                                        h2 nc01, h2 nc2z, float lind) {
  h2 drg = N.rg - C.rg;            // v_pk_add_f16 (neg)
  h2 dbd = N.bd - C.bd;
  h2 sq  = dbd*dbd;                // v_pk_mul_f16: (db^2, dd^2), pre-scaled
  float dbsq = (float)sq.x;
  float ddsq = (float)sq.y;
#if __has_builtin(__builtin_amdgcn_fdot2)
  float q  = __builtin_amdgcn_fdot2(drg, drg, dbsq, false);      // dr^2+dg^2+db^2 (scaled)
  float a1 = lind - q;
  float w1 = __builtin_amdgcn_fdot2(N.y01, nc01, 1.0f, false);   // 1 - y0Y0 - y1Y1
  float w  = __builtin_amdgcn_fdot2(N.y2m, nc2z, w1, false);     // ... - y2Y2 (m lane masked by 0)
#else
  float dr = (float)drg.x, dg = (float)drg.y;
  float a1 = fmaf(-dr, dr, fmaf(-dg, dg, lind - dbsq));
  float ny0 = (float)N.y01.x, ny1 = (float)N.y01.y, ny2 = (float)N.y2m.x;
  float cy0 = (float)C.y01.x, cy1 = (float)C.y01.y, cy2 = (float)C.y2m.x;
  float w  = fmaf(-ny0, cy0, fmaf(-ny1, cy1, fmaf(-ny2, cy2, 1.0f)));
  (void)nc01; (void)nc2z;
#endif
  float kv = __builtin_amdgcn_exp2f(a1) + __builtin_amdgcn_exp2f(-ddsq);
  return kv * w;
}

// ---------------- crf_kernel: f16 LDS tile (one-sided halo), 4 center rows/thread,
//                  db-halved blocks, DPP reductions, per-wave bin slices (no LDS atomics),
//                  fused softmax/CE + stats blocks ----------------
__global__ __launch_bounds__(256, 4) void crf_kernel(
    const float* __restrict__ logit, const int* __restrict__ target,
    const float* __restrict__ image, const float* __restrict__ depth,
    const float* __restrict__ dst,
    float* __restrict__ g_bins, float* __restrict__ g_ce,
    float* __restrict__ rowBand, float* __restrict__ colBand) {
  __shared__ PixV  tile[TPIX];
  __shared__ float binsS[4][NBINS];   // per-wave slices: plain stores, no atomics
  __shared__ float redS[12];

  int tx = threadIdx.x;
  int bid = blockIdx.x;
  int lane = tx & 63;
  int wv = tx >> 6;

  if (bid >= NCRF) {           // ---- stats path: margin band sums of dst ----
    int k = bid - NCRF;
    float s = 0.f;
    if (k < 22) {
      int row = (k < 11) ? k : (234 + k);
      for (int t = tx; t < 2048; t += 256) {
        int b = t >> 9, j = t & 511;
        s += dst[(size_t)b*HW + row*W + j];
      }
    } else {
      int kc = k - 22;
      int col = (kc < 11) ? kc : (490 + kc);
      for (int t = tx; t < 1024; t += 256) {
        int b = t >> 8, i = t & 255;
        s += dst[(size_t)b*HW + i*W + col];
      }
    }
    s = wave_sum(s);
    if (lane == 0) redS[wv] = s;
    __syncthreads();
    if (tx == 0) {
      float tot = redS[0] + redS[1] + redS[2] + redS[3];
      if (k < 22) rowBand[k] = tot; else colBand[k - 22] = tot;
    }
    return;
  }

  int tileId = bid >> 1;       // 512 tiles
  int half   = bid & 1;        // 0: db=-11..-1, 1: db=+1..+11
  int bz = tileId >> 7;        // 128 tiles per batch (8 row-tiles x 16 col-tiles)
  int rem = tileId & 127;
  int i0 = (rem >> 4) * TYR;
  int j0 = (rem & 15) * TX;
  int co = half ? 0 : 11;      // center col offset inside tile
  int cbase = j0 - co;         // global col of tile col 0

  const float* lg0 = logit + (size_t)bz*3*HW;
  const float* lg1 = lg0 + HW;
  const float* lg2 = lg0 + 2*HW;
  const float* im0 = image + (size_t)bz*3*HW;
  const float* im1 = im0 + HW;
  const float* im2 = im0 + 2*HW;
  const float* dep = depth + (size_t)bz*HW;
  const float* dsb = dst   + (size_t)bz*HW;
  const int*   tgb = target + (size_t)bz*HW;

  for (int s = tx; s < 4*NBINS; s += 256) ((float*)binsS)[s] = 0.f;

  // --- staging: global -> LDS (f16 pack, rgb/d pre-scaled) with fused softmax;
  //     CE + sum(m) only on half 0 (avoid double count) ---
  float v0 = 0.f, v1 = 0.f, v2 = 0.f;
  for (int s = tx; s < TPIX; s += 256) {
    int r = s / TCOLS, c = s - r*TCOLS;
    int gi = i0 + r, gj = cbase + c;
    PixV ph;
    if (gi < H && (unsigned)gj < (unsigned)W) {
      int q = gi*W + gj;
      float l0 = lg0[q], l1 = lg1[q], l2 = lg2[q];
      float mx = fmaxf(l0, fmaxf(l1, l2));
      float e0 = __builtin_amdgcn_exp2f((l0-mx)*LOG2E);
      float e1 = __builtin_amdgcn_exp2f((l1-mx)*LOG2E);
      float e2 = __builtin_amdgcn_exp2f((l2-mx)*LOG2E);
      float S = e0+e1+e2;
      float inv = 1.0f/S;
      float m = dsb[q];
      ph.rg  = pack2(im0[q]*KRGB, im1[q]*KRGB);
      ph.bd  = pack2(im2[q]*KRGB, dep[q]*KDEP);
      ph.y01 = pack2(e0*inv, e1*inv);
      ph.y2m = pack2(e2*inv, m);
      if (half == 0 && r < TYR && c >= co && c < co+TX) {   // center pixel, once per tile
        int t = tgb[q];
        float lt = (t==0) ? l0 : ((t==1) ? l1 : l2);
        float lce = mx + __logf(S) - lt;
        float t0 = lce * m;
        v0 += t0;
        v1 += lce - t0;
        v2 += m;
      }
    } else {
      ph.rg = ph.bd = pack2(1e30f, 1e30f);   // +inf sentinel -> kernel = 0
      ph.y01 = ph.y2m = pack2(0.f, 0.f);     // m = 0
    }
    tile[s] = ph;
  }
  __syncthreads();

  // --- main pair loop: thread owns 4 center rows; this block's 11 db offsets; both bins.
  //     One ds_read + one DPP-reduce pair per iteration covers 4 pixel-pairs.
  //     Each (db,a) bin id is written exactly once per wave -> plain ds_write to wave slice. ---
  int txc = tx & 31, ty = tx >> 5;
  int crow = ty*4;
  int cidx = crow*TCOLS + txc + co;
  PixV c0 = tile[cidx];
  PixV c1 = tile[cidx +   TCOLS];
  PixV c2 = tile[cidx + 2*TCOLS];
  PixV c3 = tile[cidx + 3*TCOLS];
  h2 nc01_0 = -c0.y01, nc01_1 = -c1.y01, nc01_2 = -c2.y01, nc01_3 = -c3.y01;
  h2 nc2z_0; nc2z_0.x = -c0.y2m.x; nc2z_0.y = (_Float16)0.f;
  h2 nc2z_1; nc2z_1.x = -c1.y2m.x; nc2z_1.y = (_Float16)0.f;
  h2 nc2z_2; nc2z_2.x = -c2.y2m.x; nc2z_2.y = (_Float16)0.f;
  h2 nc2z_3; nc2z_3.x = -c3.y2m.x; nc2z_3.y = (_Float16)0.f;
  float cm0 = (float)c0.y2m.y;
  float cm1 = (float)c1.y2m.y;
  float cm2 = (float)c2.y2m.y;
  float cm3 = (float)c3.y2m.y;

  int biLo = half * 11;        // 0..10 or 11..21
  #pragma unroll 1
  for (int bi = biLo; bi < biLo + 11; ++bi) {
    int db = bi - ((bi < 11) ? 11 : 10);   // -11..-1 (half 0), 1..11 (half 1)
    int nb = cidx + db;
    float lb = CIND * (float)(db*db);
    int bb = SPAN*KK + (db + SPAN);        // bin base; idx(+a,+db) = bb + a*KK, idx(-a,-db) = 528 - that
    // window: at iteration a, w0..w3 = rows crow+a .. crow+a+3 (w_k pairs with center k)
    PixV w0 = tile[nb +   TCOLS];
    PixV w1 = tile[nb + 2*TCOLS];
    PixV w2 = tile[nb + 3*TCOLS];
    float m0 = (float)w0.y2m.y;
    float m1 = (float)w1.y2m.y;
    float m2 = (float)w2.y2m.y;
    #pragma unroll
    for (int a = 1; a <= 11; ++a) {
      PixV w3 = tile[nb + (a+3)*TCOLS];
      float m3 = (float)w3.y2m.y;
      float lind = fmaf((float)(a*a), CIND, lb);   // a const -> folds to add
      float cc0 = paircc(c0, w0, nc01_0, nc2z_0, lind);
      float cc1 = paircc(c1, w1, nc01_1, nc2z_1, lind);
      float cc2 = paircc(c2, w2, nc01_2, nc2z_2, lind);
      float cc3 = paircc(c3, w3, nc01_3, nc2z_3, lind);
      float nd = fmaf(cc3, cm3, fmaf(cc2, cm2, fmaf(cc1, cm1, cc0*cm0)));  // bin(+a,+db), center m
      float nr = fmaf(cc3, m3,  fmaf(cc2, m2,  fmaf(cc1, m1,  cc0*m0)));  // bin(-a,-db), neighbor m
      nd = dpp_sum(nd);
      nr = dpp_sum(nr);
      if (lane == 63) {
        int id = bb + a*KK;
        binsS[wv][id]       = nd;    // plain store: id unique per wave per block
        binsS[wv][528 - id] = nr;
      }
      w0 = w1; w1 = w2; w2 = w3;
      m0 = m1; m1 = m2; m2 = m3;
    }
  }
  __syncthreads();

  // --- flush bins (sum 4 wave slices; only this half's 242 bins are nonzero) + CE (half 0) ---
  for (int s = tx; s < NBINS; s += 256) {
    float v = (binsS[0][s] + binsS[1][s]) + (binsS[2][s] + binsS[3][s]);
    if (v != 0.f) unsafeAtomicAdd(&g_bins[s], v);
  }
  if (half == 0) {
    v0 = dpp_sum(v0); v1 = dpp_sum(v1); v2 = dpp_sum(v2);
    if (lane == 63) { redS[wv] = v0; redS[4+wv] = v1; redS[8+wv] = v2; }
    __syncthreads();
    if (tx == 0) {
      unsafeAtomicAdd(&g_ce[0], redS[0]+redS[1]+redS[2]+redS[3]);
      unsafeAtomicAdd(&g_ce[1], redS[4]+redS[5]+redS[6]+redS[7]);
      unsafeAtomicAdd(&g_ce[2], redS[8]+redS[9]+redS[10]+redS[11]);
    }
  }
}

// ---------------- fin_kernel: analytic denominators via 2D prefix sum (inclusion-exclusion) ----------------
__global__ __launch_bounds__(256) void fin_kernel(const float* __restrict__ g_bins,
                                                  const float* __restrict__ g_ce,
                                                  const float* __restrict__ rowBand,
                                                  const float* __restrict__ colBand,
                                                  const float* __restrict__ dst,
                                                  float* __restrict__ out) {
  __shared__ float corner[22][22];
  __shared__ float rowp[22][23];     // exclusive row prefixes of corner
  __shared__ float P[23][23];        // exclusive 2D prefix: P[i][j] = sum_{r<i,c<j} corner[r][c]
  __shared__ float rb[22], cb[22];
  __shared__ float TopP[12], BotS[12], LeftP[12], RightS[12];
  __shared__ float red[4];
  int tx = threadIdx.x;
  if (tx < 22) { rb[tx] = rowBand[tx]; cb[tx] = colBand[tx]; }
  for (int t = tx; t < 484; t += 256) {
    int ri = t / 22, ci = t - ri*22;
    int row = (ri < 11) ? ri : (234 + ri);
    int col = (ci < 11) ? ci : (490 + ci);
    float s = 0.f;
    #pragma unroll
    for (int b = 0; b < 4; ++b) s += dst[(size_t)b*HW + row*W + col];
    corner[ri][ci] = s;
  }
  __syncthreads();

  if (tx < 22) {
    float p = 0.f; rowp[tx][0] = 0.f;
    for (int j = 0; j < 22; ++j) { p += corner[tx][j]; rowp[tx][j+1] = p; }
  }
  else if (tx == 32) { float p=0.f; TopP[0]=0.f;   for (int k=1;k<12;++k){ p += rb[k-1];  TopP[k]=p; } }
  else if (tx == 33) { float p=0.f; BotS[0]=0.f;   for (int k=1;k<12;++k){ p += rb[22-k]; BotS[k]=p; } }
  else if (tx == 34) { float p=0.f; LeftP[0]=0.f;  for (int k=1;k<12;++k){ p += cb[k-1];  LeftP[k]=p; } }
  else if (tx == 35) { float p=0.f; RightS[0]=0.f; for (int k=1;k<12;++k){ p += cb[22-k]; RightS[k]=p; } }
  __syncthreads();

  if (tx < 23) {
    float p = 0.f; P[0][tx] = 0.f;
    for (int i = 0; i < 22; ++i) { p += rowp[i][tx]; P[i+1][tx] = p; }
  }
  __syncthreads();

  float S = g_ce[2];   // sum of dst over everything
  float esum = 0.f;
  for (int od = tx; od < NBINS; od += 256) {
    int dxp = od / KK, dyp = od - dxp*KK;
    int dx = dxp - SPAN, dy = dyp - SPAN;
    if (dx != 0 && dy != 0) {
      int ax = (dx < 0) ? -dx : 0;
      int bx = (dx > 0) ?  dx : 0;
      int ay = (dy < 0) ? -dy : 0;
      int by = (dy > 0) ?  dy : 0;
      float TLv = P[ax][ay];
      float TRv = P[ax][22] - P[ax][22-by];
      float BLv = P[22][ay] - P[22-bx][ay];
      float BRv = P[22][22] - P[22-bx][22] - P[22][22-by] + P[22-bx][22-by];
      float den = S - TopP[ax] - BotS[bx] - LeftP[ay] - RightS[by]
                + TLv + TRv + BLv + BRv;
      esum += g_bins[od] / den;
    }
  }
  esum = wave_sum(esum);
  int lane = tx & 63, wv = tx >> 6;
  if (lane == 0) red[wv] = esum;
  __syncthreads();
  if (tx == 0) {
    float E = (red[0]+red[1]+red[2]+red[3]) / 529.0f;
    float count = S / NPIXF;
    float l1 = g_ce[0] / NPIXF;
    float l2 = g_ce[1] / NPIXF;
    out[0] = l1*(1.0f - count) + l2*count;
    out[1] = E;
  }
}

extern "C" void kernel_launch(void* const* d_in, const int* in_sizes, int n_in,
                              void* d_out, int out_size, void* d_ws, size_t ws_size,
                              hipStream_t stream) {
  const float* logit  = (const float*)d_in[0];
  const int*   target = (const int*)  d_in[1];
  const float* image  = (const float*)d_in[2];
  const float* depth  = (const float*)d_in[3];
  const float* dstm   = (const float*)d_in[4];
  float* out = (float*)d_out;

  float* ws      = (float*)d_ws;
  float* g_bins  = ws;             // 529
  float* g_ce    = ws + NBINS;     // 3  (sum lce*m, sum lce*(1-m), sum m)
  float* rowBand = ws + 532;       // 22
  float* colBand = ws + 554;       // 22

  hipMemsetAsync(ws, 0, 532*sizeof(float), stream);
  crf_kernel<<<NCRF + NSTAT, 256, 0, stream>>>(logit, target, image, depth, dstm,
                                               g_bins, g_ce, rowBand, colBand);
  fin_kernel<<<1, 256, 0, stream>>>(g_bins, g_ce, rowBand, colBand, dstm, out);
}

// Round 15
// 164.021 us; speedup vs baseline: 1.1787x; 1.0615x over previous
//
#include <hip/hip_runtime.h>
#include <hip/hip_fp16.h>

#define H 256
#define W 512
#define HW (H*W)
#define NPIXF 524288.0f
#define SPAN 11
#define KK 23
#define NBINS (KK*KK)   // 529

#define LOG2E 1.4426950408889634f
#define CEXP  (-0.7213475204444817f)   // -0.5*log2(e)
#define CIND  (CEXP/36.0f)             // 1/SIG_XY^2
// sqrt(|CEXP|*100) and sqrt(|CEXP|*25): fold rgb/depth sigma scaling into staged f16 data
#define KRGB  8.4932180f
#define KDEP  4.2466090f

// tile geometry: center 32 cols x 32 rows, halo +11 rows below, one-sided 11-col halo.
// LDS is ROW-PAIR packed SoA: pair q covers rows (2q-apar, 2q+1-apar).
#define TX 32
#define TYR 32
#define TROWS 43          // rows 0..42
#define TCOLS 43          // TX + 11 (one-sided halo)
#define NP 22             // row pairs

#define NTILE 512         // 4 batches x 8 rowtiles x 16 coltiles
#define NCRF (NTILE*4)    // 4 blocks per tile: (db half) x (a parity)
#define NSTAT 44

typedef _Float16 h2 __attribute__((ext_vector_type(2)));

struct alignas(16) Pk1 { h2 rr, gg, bb, dd; };   // rgb,d (pre-scaled) for 2 rows
struct alignas(16) Pk2 { h2 y0, y1, y2, mm; };   // softmax probs + mask for 2 rows

__device__ __forceinline__ h2 pack2(float a, float b) {
  h2 r; r.x = (_Float16)a; r.y = (_Float16)b; return r;
}

__device__ __forceinline__ h2 exp2pk(h2 x) {
  __half2 hx = __builtin_bit_cast(__half2, x);
  __half2 hr = h2exp2(hx);
  return __builtin_bit_cast(h2, hr);
}

// build h2(lo = a.hi, hi = b.lo) — phase-1 center assembly (setup only)
__device__ __forceinline__ h2 alignh(h2 a, h2 b) { h2 r; r.x = a.y; r.y = b.x; return r; }
__device__ __forceinline__ Pk1 alignP1(const Pk1& a, const Pk1& b) {
  Pk1 r; r.rr = alignh(a.rr,b.rr); r.gg = alignh(a.gg,b.gg);
  r.bb = alignh(a.bb,b.bb); r.dd = alignh(a.dd,b.dd); return r;
}
__device__ __forceinline__ Pk2 alignP2(const Pk2& a, const Pk2& b) {
  Pk2 r; r.y0 = alignh(a.y0,b.y0); r.y1 = alignh(a.y1,b.y1);
  r.y2 = alignh(a.y2,b.y2); r.mm = alignh(a.mm,b.mm); return r;
}

__device__ __forceinline__ float fdot2f(h2 a, h2 b, float c) {
#if __has_builtin(__builtin_amdgcn_fdot2)
  return __builtin_amdgcn_fdot2(a, b, c, false);
#else
  return c + (float)a.x*(float)b.x + (float)a.y*(float)b.y;
#endif
}

// 64-lane sum on the VALU pipe (DPP). Total lands in lane 63.
__device__ __forceinline__ float dpp_sum(float x) {
  x += __int_as_float(__builtin_amdgcn_update_dpp(0, __float_as_int(x), 0x111, 0xf, 0xf, true)); // row_shr:1
  x += __int_as_float(__builtin_amdgcn_update_dpp(0, __float_as_int(x), 0x112, 0xf, 0xf, true)); // row_shr:2
  x += __int_as_float(__builtin_amdgcn_update_dpp(0, __float_as_int(x), 0x114, 0xf, 0xf, true)); // row_shr:4
  x += __int_as_float(__builtin_amdgcn_update_dpp(0, __float_as_int(x), 0x118, 0xf, 0xf, true)); // row_shr:8
  x += __int_as_float(__builtin_amdgcn_update_dpp(0, __float_as_int(x), 0x142, 0xa, 0xf, true)); // row_bcast:15
  x += __int_as_float(__builtin_amdgcn_update_dpp(0, __float_as_int(x), 0x143, 0xc, 0xf, true)); // row_bcast:31
  return x;
}

__device__ __forceinline__ float wave_sum(float x) {
  #pragma unroll
  for (int s = 1; s < 64; s <<= 1) x += __shfl_xor(x, s, 64);
  return x;
}

// packed pair compatibility: cc for 2 pairs at once (lo/hi halves)
__device__ __forceinline__ h2 ccpk(const Pk1& C1, const Pk2& C2,
                                   const Pk1& W1, const Pk2& W2, h2 lpk) {
  h2 dr  = W1.rr - C1.rr;
  h2 dg  = W1.gg - C1.gg;
  h2 dbv = W1.bb - C1.bb;
  h2 dd  = W1.dd - C1.dd;
  h2 rs  = dr*dr + dg*dg + dbv*dbv;   // pk fma chain (pre-scaled)
  h2 a1  = lpk - rs;
  h2 a2  = -(dd*dd);
  h2 kv  = exp2pk(a1) + exp2pk(a2);
  h2 one; one.x = (_Float16)1.f; one.y = (_Float16)1.f;
  h2 w   = one - W2.y0*C2.y0 - W2.y1*C2.y1 - W2.y2*C2.y2;
  return kv * w;
}

// main pair loop, a-parity templated (APAR=0: a in {2,4,6,8,10}; APAR=1: a in {1..11 odd})
template<int APAR>
__device__ __forceinline__ void pairLoop(const Pk1* t1, const Pk2* t2,
                                         float (*binsS)[NBINS], int tx, int half) {
  int lane = tx & 63, wv = tx >> 6;
  int txc = tx & 31, ty = tx >> 5;
  int crow = ty*4;
  int q0 = crow >> 1;
  int co = half ? 0 : 11;
  int ccol = txc + co;

  Pk1 cA1, cB1; Pk2 cA2, cB2;
  if (APAR == 0) {
    cA1 = t1[q0*TCOLS + ccol];      cA2 = t2[q0*TCOLS + ccol];
    cB1 = t1[(q0+1)*TCOLS + ccol];  cB2 = t2[(q0+1)*TCOLS + ccol];
  } else {
    Pk1 pa = t1[q0*TCOLS+ccol], pb = t1[(q0+1)*TCOLS+ccol], pc = t1[(q0+2)*TCOLS+ccol];
    Pk2 qa = t2[q0*TCOLS+ccol], qb = t2[(q0+1)*TCOLS+ccol], qc = t2[(q0+2)*TCOLS+ccol];
    cA1 = alignP1(pa, pb); cB1 = alignP1(pb, pc);
    cA2 = alignP2(qa, qb); cB2 = alignP2(qb, qc);
  }

  int biLo = half * 11;
  #pragma unroll 1
  for (int bi = biLo; bi < biLo + 11; ++bi) {
    int db = bi - ((bi < 11) ? 11 : 10);   // -11..-1 (half 0), 1..11 (half 1)
    int nbcol = ccol + db;                 // stays in [0,42]
    float lb = CIND * (float)(db*db);
    int bb = SPAN*KK + (db + SPAN);        // idx(+a,+db) = bb + a*KK; idx(-a,-db) = 528 - that
    int qw = q0 + 1;                       // first window pair index
    Pk1 wA1 = t1[qw*TCOLS + nbcol];      Pk2 wA2 = t2[qw*TCOLS + nbcol];
    Pk1 wB1 = t1[(qw+1)*TCOLS + nbcol];  Pk2 wB2 = t2[(qw+1)*TCOLS + nbcol];
    constexpr int NS = APAR ? 6 : 5;
    #pragma unroll
    for (int s = 0; s < NS; ++s) {
      if (s > 0) {
        wA1 = wB1; wA2 = wB2;
        wB1 = t1[(qw+s+1)*TCOLS + nbcol]; wB2 = t2[(qw+s+1)*TCOLS + nbcol];
      }
      int a = APAR ? (2*s+1) : (2*s+2);
      float lind = fmaf((float)(a*a), CIND, lb);
      h2 lpk = pack2(lind, lind);
      h2 ccA = ccpk(cA1, cA2, wA1, wA2, lpk);   // pairs: rows (crow,crow+1) vs +a
      h2 ccB = ccpk(cB1, cB2, wB1, wB2, lpk);   // pairs: rows (crow+2,crow+3) vs +a
      float nd = fdot2f(ccA, cA2.mm, 0.f);      // center-m weighted
      nd = fdot2f(ccB, cB2.mm, nd);
      float nr = fdot2f(ccA, wA2.mm, 0.f);      // neighbor-m weighted
      nr = fdot2f(ccB, wB2.mm, nr);
      nd = dpp_sum(nd); nr = dpp_sum(nr);
      if (lane == 63) {
        int id = bb + a*KK;
        binsS[wv][id]       = nd;   // plain store: (db,a) unique per wave per block
        binsS[wv][528 - id] = nr;
      }
    }
  }
}

// ---------------- crf_kernel: row-pair packed f16 SoA tile, 4 center rows/thread,
//                  (db half x a parity) blocks, pk pair math, per-wave bin slices ----------------
__global__ __launch_bounds__(256, 4) void crf_kernel(
    const float* __restrict__ logit, const int* __restrict__ target,
    const float* __restrict__ image, const float* __restrict__ depth,
    const float* __restrict__ dst,
    float* __restrict__ g_bins, float* __restrict__ g_ce,
    float* __restrict__ rowBand, float* __restrict__ colBand) {
  __shared__ Pk1 t1[NP*TCOLS];        // 15.1 KB
  __shared__ Pk2 t2[NP*TCOLS];        // 15.1 KB
  __shared__ float binsS[4][NBINS];   // 8.5 KB, per-wave slices
  __shared__ float redS[12];

  int tx = threadIdx.x;
  int bid = blockIdx.x;
  int lane = tx & 63;
  int wv = tx >> 6;

  if (bid >= NCRF) {           // ---- stats path: margin band sums of dst ----
    int k = bid - NCRF;
    float s = 0.f;
    if (k < 22) {
      int row = (k < 11) ? k : (234 + k);
      for (int t = tx; t < 2048; t += 256) {
        int b = t >> 9, j = t & 511;
        s += dst[(size_t)b*HW + row*W + j];
      }
    } else {
      int kc = k - 22;
      int col = (kc < 11) ? kc : (490 + kc);
      for (int t = tx; t < 1024; t += 256) {
        int b = t >> 8, i = t & 255;
        s += dst[(size_t)b*HW + i*W + col];
      }
    }
    s = wave_sum(s);
    if (lane == 0) redS[wv] = s;
    __syncthreads();
    if (tx == 0) {
      float tot = redS[0] + redS[1] + redS[2] + redS[3];
      if (k < 22) rowBand[k] = tot; else colBand[k - 22] = tot;
    }
    return;
  }

  int tileId = bid >> 2;       // 512 tiles
  int sub    = bid & 3;
  int half   = sub >> 1;       // 0: db<0, 1: db>0
  int apar   = sub & 1;        // 0: even a, 1: odd a
  int bz = tileId >> 7;        // 128 tiles per batch
  int rem = tileId & 127;
  int i0 = (rem >> 4) * TYR;
  int j0 = (rem & 15) * TX;
  int co = half ? 0 : 11;
  int cbase = j0 - co;         // global col of tile col 0
  bool ceB = (half == 0) && (apar == 0);   // CE once per tile

  const float* lg0 = logit + (size_t)bz*3*HW;
  const float* lg1 = lg0 + HW;
  const float* lg2 = lg0 + 2*HW;
  const float* im0 = image + (size_t)bz*3*HW;
  const float* im1 = im0 + HW;
  const float* im2 = im0 + 2*HW;
  const float* dep = depth + (size_t)bz*HW;
  const float* dsb = dst   + (size_t)bz*HW;
  const int*   tgb = target + (size_t)bz*HW;

  for (int s = tx; s < 4*NBINS; s += 256) ((float*)binsS)[s] = 0.f;

  // --- staging: global -> LDS row-pair SoA (phase = apar) with fused softmax; CE on one block/tile ---
  float v0 = 0.f, v1 = 0.f, v2 = 0.f;
  for (int s = tx; s < NP*TCOLS; s += 256) {
    int q = s / TCOLS, c = s - q*TCOLS;
    int gj = cbase + c;
    float fr[2], fg[2], fb[2], fd[2], f0[2], f1[2], f2[2], fm[2];
    #pragma unroll
    for (int hh = 0; hh < 2; ++hh) {
      int r = 2*q - apar + hh;           // tile row of this half
      int gi = i0 + r;
      bool ok = (r >= 0) && (r < TROWS) && (gi < H) && ((unsigned)gj < (unsigned)W);
      if (ok) {
        int qq = gi*W + gj;
        float l0 = lg0[qq], l1 = lg1[qq], l2 = lg2[qq];
        float mx = fmaxf(l0, fmaxf(l1, l2));
        float e0 = __builtin_amdgcn_exp2f((l0-mx)*LOG2E);
        float e1 = __builtin_amdgcn_exp2f((l1-mx)*LOG2E);
        float e2 = __builtin_amdgcn_exp2f((l2-mx)*LOG2E);
        float S = e0+e1+e2;
        float inv = 1.0f/S;
        float m = dsb[qq];
        fr[hh] = im0[qq]*KRGB; fg[hh] = im1[qq]*KRGB;
        fb[hh] = im2[qq]*KRGB; fd[hh] = dep[qq]*KDEP;
        f0[hh] = e0*inv; f1[hh] = e1*inv; f2[hh] = e2*inv; fm[hh] = m;
        if (ceB && r < TYR && c >= co && c < co+TX) {   // center pixel, once per tile
          int t = tgb[qq];
          float lt = (t==0) ? l0 : ((t==1) ? l1 : l2);
          float lce = mx + __logf(S) - lt;
          float t0 = lce * m;
          v0 += t0;
          v1 += lce - t0;
          v2 += m;
        }
      } else {
        fr[hh] = fg[hh] = fb[hh] = fd[hh] = 1e30f;   // +inf sentinel -> kernel = 0
        f0[hh] = f1[hh] = f2[hh] = fm[hh] = 0.f;     // m = 0
      }
    }
    Pk1 p1; p1.rr = pack2(fr[0],fr[1]); p1.gg = pack2(fg[0],fg[1]);
            p1.bb = pack2(fb[0],fb[1]); p1.dd = pack2(fd[0],fd[1]);
    Pk2 p2; p2.y0 = pack2(f0[0],f0[1]); p2.y1 = pack2(f1[0],f1[1]);
            p2.y2 = pack2(f2[0],f2[1]); p2.mm = pack2(fm[0],fm[1]);
    t1[s] = p1; t2[s] = p2;
  }
  __syncthreads();

  if (apar == 0) pairLoop<0>(t1, t2, binsS, tx, half);
  else           pairLoop<1>(t1, t2, binsS, tx, half);
  __syncthreads();

  // --- flush bins (sum 4 wave slices; only this block's ~120 bins nonzero) + CE ---
  for (int s = tx; s < NBINS; s += 256) {
    float v = (binsS[0][s] + binsS[1][s]) + (binsS[2][s] + binsS[3][s]);
    if (v != 0.f) unsafeAtomicAdd(&g_bins[s], v);
  }
  if (ceB) {
    v0 = dpp_sum(v0); v1 = dpp_sum(v1); v2 = dpp_sum(v2);
    if (lane == 63) { redS[wv] = v0; redS[4+wv] = v1; redS[8+wv] = v2; }
    __syncthreads();
    if (tx == 0) {
      unsafeAtomicAdd(&g_ce[0], redS[0]+redS[1]+redS[2]+redS[3]);
      unsafeAtomicAdd(&g_ce[1], redS[4]+redS[5]+redS[6]+redS[7]);
      unsafeAtomicAdd(&g_ce[2], redS[8]+redS[9]+redS[10]+redS[11]);
    }
  }
}

// ---------------- fin_kernel: analytic denominators via 2D prefix sum (inclusion-exclusion) ----------------
__global__ __launch_bounds__(256) void fin_kernel(const float* __restrict__ g_bins,
                                                  const float* __restrict__ g_ce,
                                                  const float* __restrict__ rowBand,
                                                  const float* __restrict__ colBand,
                                                  const float* __restrict__ dst,
                                                  float* __restrict__ out) {
  __shared__ float corner[22][22];
  __shared__ float rowp[22][23];     // exclusive row prefixes of corner
  __shared__ float P[23][23];        // exclusive 2D prefix: P[i][j] = sum_{r<i,c<j} corner[r][c]
  __shared__ float rb[22], cb[22];
  __shared__ float TopP[12], BotS[12], LeftP[12], RightS[12];
  __shared__ float red[4];
  int tx = threadIdx.x;
  if (tx < 22) { rb[tx] = rowBand[tx]; cb[tx] = colBand[tx]; }
  for (int t = tx; t < 484; t += 256) {
    int ri = t / 22, ci = t - ri*22;
    int row = (ri < 11) ? ri : (234 + ri);
    int col = (ci < 11) ? ci : (490 + ci);
    float s = 0.f;
    #pragma unroll
    for (int b = 0; b < 4; ++b) s += dst[(size_t)b*HW + row*W + col];
    corner[ri][ci] = s;
  }
  __syncthreads();

  if (tx < 22) {
    float p = 0.f; rowp[tx][0] = 0.f;
    for (int j = 0; j < 22; ++j) { p += corner[tx][j]; rowp[tx][j+1] = p; }
  }
  else if (tx == 32) { float p=0.f; TopP[0]=0.f;   for (int k=1;k<12;++k){ p += rb[k-1];  TopP[k]=p; } }
  else if (tx == 33) { float p=0.f; BotS[0]=0.f;   for (int k=1;k<12;++k){ p += rb[22-k]; BotS[k]=p; } }
  else if (tx == 34) { float p=0.f; LeftP[0]=0.f;  for (int k=1;k<12;++k){ p += cb[k-1];  LeftP[k]=p; } }
  else if (tx == 35) { float p=0.f; RightS[0]=0.f; for (int k=1;k<12;++k){ p += cb[22-k]; RightS[k]=p; } }
  __syncthreads();

  if (tx < 23) {
    float p = 0.f; P[0][tx] = 0.f;
    for (int i = 0; i < 22; ++i) { p += rowp[i][tx]; P[i+1][tx] = p; }
  }
  __syncthreads();

  float S = g_ce[2];   // sum of dst over everything
  float esum = 0.f;
  for (int od = tx; od < NBINS; od += 256) {
    int dxp = od / KK, dyp = od - dxp*KK;
    int dx = dxp - SPAN, dy = dyp - SPAN;
    if (dx != 0 && dy != 0) {
      int ax = (dx < 0) ? -dx : 0;
      int bx = (dx > 0) ?  dx : 0;
      int ay = (dy < 0) ? -dy : 0;
      int by = (dy > 0) ?  dy : 0;
      float TLv = P[ax][ay];
      float TRv = P[ax][22] - P[ax][22-by];
      float BLv = P[22][ay] - P[22-bx][ay];
      float BRv = P[22][22] - P[22-bx][22] - P[22][22-by] + P[22-bx][22-by];
      float den = S - TopP[ax] - BotS[bx] - LeftP[ay] - RightS[by]
                + TLv + TRv + BLv + BRv;
      esum += g_bins[od] / den;
    }
  }
  esum = wave_sum(esum);
  int lane = tx & 63, wv = tx >> 6;
  if (lane == 0) red[wv] = esum;
  __syncthreads();
  if (tx == 0) {
    float E = (red[0]+red[1]+red[2]+red[3]) / 529.0f;
    float count = S / NPIXF;
    float l1 = g_ce[0] / NPIXF;
    float l2 = g_ce[1] / NPIXF;
    out[0] = l1*(1.0f - count) + l2*count;
    out[1] = E;
  }
}

extern "C" void kernel_launch(void* const* d_in, const int* in_sizes, int n_in,
                              void* d_out, int out_size, void* d_ws, size_t ws_size,
                              hipStream_t stream) {
  const float* logit  = (const float*)d_in[0];
  const int*   target = (const int*)  d_in[1];
  const float* image  = (const float*)d_in[2];
  const float* depth  = (const float*)d_in[3];
  const float* dstm   = (const float*)d_in[4];
  float* out = (float*)d_out;

  float* ws      = (float*)d_ws;
  float* g_bins  = ws;             // 529
  float* g_ce    = ws + NBINS;     // 3  (sum lce*m, sum lce*(1-m), sum m)
  float* rowBand = ws + 532;       // 22
  float* colBand = ws + 554;       // 22

  hipMemsetAsync(ws, 0, 532*sizeof(float), stream);
  crf_kernel<<<NCRF + NSTAT, 256, 0, stream>>>(logit, target, image, depth, dstm,
                                               g_bins, g_ce, rowBand, colBand);
  fin_kernel<<<1, 256, 0, stream>>>(g_bins, g_ce, rowBand, colBand, dstm, out);
}

// Round 17
// 162.214 us; speedup vs baseline: 1.1918x; 1.0111x over previous
//
#include <hip/hip_runtime.h>
#include <hip/hip_fp16.h>

#define H 256
#define W 512
#define HW (H*W)
#define NPIXF 524288.0f
#define SPAN 11
#define KK 23
#define NBINS (KK*KK)   // 529

#define LOG2E 1.4426950408889634f
#define CEXP  (-0.7213475204444817f)   // -0.5*log2(e)
#define CIND  (CEXP/36.0f)             // 1/SIG_XY^2
// sqrt(|CEXP|*100) and sqrt(|CEXP|*25): fold rgb/depth sigma scaling into staged f16 data
#define KRGB  8.4932180f
#define KDEP  4.2466090f

// tile geometry: center 32 cols x 32 rows, halo +11 rows below, one-sided 11-col halo.
// LDS is ROW-PAIR packed SoA: pair q covers rows (2q-apar, 2q+1-apar).
#define TX 32
#define TYR 32
#define TROWS 43          // rows 0..42
#define TCOLS 43          // TX + 11 (one-sided halo)
#define NP 22             // row pairs

#define NTILE 512         // 4 batches x 8 rowtiles x 16 coltiles
#define NCRF (NTILE*4)    // 4 blocks per tile: (db half) x (a parity)
#define NSTAT 44

typedef _Float16 h2 __attribute__((ext_vector_type(2)));

struct alignas(16) Pk1 { h2 rr, gg, bb, dd; };   // rgb,d (pre-scaled) for 2 rows
struct alignas(16) Pk2 { h2 y0, y1, y2, mm; };   // softmax probs + mask for 2 rows

__device__ __forceinline__ h2 pack2(float a, float b) {
  h2 r; r.x = (_Float16)a; r.y = (_Float16)b; return r;
}

__device__ __forceinline__ h2 exp2pk(h2 x) {
  __half2 hx = __builtin_bit_cast(__half2, x);
  __half2 hr = h2exp2(hx);
  return __builtin_bit_cast(h2, hr);
}

// build h2(lo = a.hi, hi = b.lo) — phase-1 center assembly (setup only)
__device__ __forceinline__ h2 alignh(h2 a, h2 b) { h2 r; r.x = a.y; r.y = b.x; return r; }
__device__ __forceinline__ Pk1 alignP1(const Pk1& a, const Pk1& b) {
  Pk1 r; r.rr = alignh(a.rr,b.rr); r.gg = alignh(a.gg,b.gg);
  r.bb = alignh(a.bb,b.bb); r.dd = alignh(a.dd,b.dd); return r;
}
__device__ __forceinline__ Pk2 alignP2(const Pk2& a, const Pk2& b) {
  Pk2 r; r.y0 = alignh(a.y0,b.y0); r.y1 = alignh(a.y1,b.y1);
  r.y2 = alignh(a.y2,b.y2); r.mm = alignh(a.mm,b.mm); return r;
}

__device__ __forceinline__ float fdot2f(h2 a, h2 b, float c) {
#if __has_builtin(__builtin_amdgcn_fdot2)
  return __builtin_amdgcn_fdot2(a, b, c, false);
#else
  return c + (float)a.x*(float)b.x + (float)a.y*(float)b.y;
#endif
}

// pack two f32 into packed f16 (one v_cvt_pkrtz_f16_f32).
// NOTE: the builtin returns __fp16 ext_vector_type(2) — bit_cast, don't construct __half2.
__device__ __forceinline__ h2 pkrtz(float a, float b) {
#if __has_builtin(__builtin_amdgcn_cvt_pkrtz)
  auto r = __builtin_amdgcn_cvt_pkrtz(a, b);
  return __builtin_bit_cast(h2, r);
#else
  return pack2(a, b);
#endif
}

// 64-lane sum on the VALU pipe (DPP). Total lands in lane 63.
__device__ __forceinline__ float dpp_sum(float x) {
  x += __int_as_float(__builtin_amdgcn_update_dpp(0, __float_as_int(x), 0x111, 0xf, 0xf, true)); // row_shr:1
  x += __int_as_float(__builtin_amdgcn_update_dpp(0, __float_as_int(x), 0x112, 0xf, 0xf, true)); // row_shr:2
  x += __int_as_float(__builtin_amdgcn_update_dpp(0, __float_as_int(x), 0x114, 0xf, 0xf, true)); // row_shr:4
  x += __int_as_float(__builtin_amdgcn_update_dpp(0, __float_as_int(x), 0x118, 0xf, 0xf, true)); // row_shr:8
  x += __int_as_float(__builtin_amdgcn_update_dpp(0, __float_as_int(x), 0x142, 0xa, 0xf, true)); // row_bcast:15
  x += __int_as_float(__builtin_amdgcn_update_dpp(0, __float_as_int(x), 0x143, 0xc, 0xf, true)); // row_bcast:31
  return x;
}

// packed-f16 64-lane sum (single DPP chain, v_pk_add_f16). Total lands in lane 63.
__device__ __forceinline__ h2 dpp_sum_pk(h2 x) {
  #define STEP(ctl, rmask) x = x + __builtin_bit_cast(h2, __builtin_amdgcn_update_dpp(0, __builtin_bit_cast(int, x), ctl, rmask, 0xf, true));
  STEP(0x111, 0xf)   // row_shr:1
  STEP(0x112, 0xf)   // row_shr:2
  STEP(0x114, 0xf)   // row_shr:4
  STEP(0x118, 0xf)   // row_shr:8
  STEP(0x142, 0xa)   // row_bcast:15
  STEP(0x143, 0xc)   // row_bcast:31
  #undef STEP
  return x;
}

__device__ __forceinline__ float wave_sum(float x) {
  #pragma unroll
  for (int s = 1; s < 64; s <<= 1) x += __shfl_xor(x, s, 64);
  return x;
}

// packed pair compatibility: cc for 2 pairs at once (lo/hi halves)
__device__ __forceinline__ h2 ccpk(const Pk1& C1, const Pk2& C2,
                                   const Pk1& W1, const Pk2& W2, h2 lpk) {
  h2 dr  = W1.rr - C1.rr;
  h2 dg  = W1.gg - C1.gg;
  h2 dbv = W1.bb - C1.bb;
  h2 dd  = W1.dd - C1.dd;
  h2 rs  = dr*dr + dg*dg + dbv*dbv;   // pk fma chain (pre-scaled)
  h2 a1  = lpk - rs;
  h2 a2  = -(dd*dd);
  h2 kv  = exp2pk(a1) + exp2pk(a2);
  h2 one; one.x = (_Float16)1.f; one.y = (_Float16)1.f;
  h2 w   = one - W2.y0*C2.y0 - W2.y1*C2.y1 - W2.y2*C2.y2;
  return kv * w;
}

// main pair loop, a-parity templated (APAR=0: a in {2,4,6,8,10}; APAR=1: a in {1..11 odd}).
// (db,a) wave-sums stored packed (nd,nr) in binsPk[wave][dbi*8+s] — every valid slot written.
template<int APAR>
__device__ __forceinline__ void pairLoop(const Pk1* t1, const Pk2* t2,
                                         unsigned (*binsPk)[96], int tx, int half) {
  int lane = tx & 63, wv = tx >> 6;
  int txc = tx & 31, ty = tx >> 5;
  int crow = ty*4;
  int q0 = crow >> 1;
  int co = half ? 0 : 11;
  int ccol = txc + co;

  Pk1 cA1, cB1; Pk2 cA2, cB2;
  if (APAR == 0) {
    cA1 = t1[q0*TCOLS + ccol];      cA2 = t2[q0*TCOLS + ccol];
    cB1 = t1[(q0+1)*TCOLS + ccol];  cB2 = t2[(q0+1)*TCOLS + ccol];
  } else {
    Pk1 pa = t1[q0*TCOLS+ccol], pb = t1[(q0+1)*TCOLS+ccol], pc = t1[(q0+2)*TCOLS+ccol];
    Pk2 qa = t2[q0*TCOLS+ccol], qb = t2[(q0+1)*TCOLS+ccol], qc = t2[(q0+2)*TCOLS+ccol];
    cA1 = alignP1(pa, pb); cB1 = alignP1(pb, pc);
    cA2 = alignP2(qa, qb); cB2 = alignP2(qb, qc);
  }

  int biLo = half * 11;
  #pragma unroll 1
  for (int bi = biLo; bi < biLo + 11; ++bi) {
    int db = bi - ((bi < 11) ? 11 : 10);   // -11..-1 (half 0), 1..11 (half 1)
    int dbi = bi - biLo;                   // 0..10
    int nbcol = ccol + db;                 // stays in [0,42]
    float lb = CIND * (float)(db*db);
    int qw = q0 + 1;                       // first window pair index
    Pk1 wA1 = t1[qw*TCOLS + nbcol];      Pk2 wA2 = t2[qw*TCOLS + nbcol];
    Pk1 wB1 = t1[(qw+1)*TCOLS + nbcol];  Pk2 wB2 = t2[(qw+1)*TCOLS + nbcol];
    constexpr int NS = APAR ? 6 : 5;
    #pragma unroll
    for (int s = 0; s < NS; ++s) {
      if (s > 0) {
        wA1 = wB1; wA2 = wB2;
        wB1 = t1[(qw+s+1)*TCOLS + nbcol]; wB2 = t2[(qw+s+1)*TCOLS + nbcol];
      }
      int a = APAR ? (2*s+1) : (2*s+2);
      float lind = fmaf((float)(a*a), CIND, lb);
      h2 lpk = pack2(lind, lind);
      h2 ccA = ccpk(cA1, cA2, wA1, wA2, lpk);   // pairs: rows (crow,crow+1) vs +a
      h2 ccB = ccpk(cB1, cB2, wB1, wB2, lpk);   // pairs: rows (crow+2,crow+3) vs +a
      float nd = fdot2f(ccA, cA2.mm, 0.f);      // center-m weighted
      nd = fdot2f(ccB, cB2.mm, nd);
      float nr = fdot2f(ccA, wA2.mm, 0.f);      // neighbor-m weighted
      nr = fdot2f(ccB, wB2.mm, nr);
      h2 pk = dpp_sum_pk(pkrtz(nd, nr));        // single packed DPP chain
      if (lane == 63)
        binsPk[wv][dbi*8 + s] = __builtin_bit_cast(unsigned, pk);
    }
  }
}

// ---------------- crf_kernel: row-pair packed f16 SoA tile, 4 center rows/thread,
//                  (db half x a parity) blocks, pk pair math, packed-f16 wave reduction ----------------
__global__ __launch_bounds__(256, 4) void crf_kernel(
    const float* __restrict__ logit, const int* __restrict__ target,
    const float* __restrict__ image, const float* __restrict__ depth,
    const float* __restrict__ dst,
    float* __restrict__ g_bins, float* __restrict__ g_ce,
    float* __restrict__ rowBand, float* __restrict__ colBand) {
  __shared__ Pk1 t1[NP*TCOLS];          // 15.1 KB
  __shared__ Pk2 t2[NP*TCOLS];          // 15.1 KB
  __shared__ unsigned binsPk[4][96];    // 1.5 KB: per-wave packed (nd,nr), lid = dbi*8+s
  __shared__ float redS[12];

  int tx = threadIdx.x;
  int bid = blockIdx.x;
  int lane = tx & 63;
  int wv = tx >> 6;

  if (bid >= NCRF) {           // ---- stats path: margin band sums of dst ----
    int k = bid - NCRF;
    float s = 0.f;
    if (k < 22) {
      int row = (k < 11) ? k : (234 + k);
      for (int t = tx; t < 2048; t += 256) {
        int b = t >> 9, j = t & 511;
        s += dst[(size_t)b*HW + row*W + j];
      }
    } else {
      int kc = k - 22;
      int col = (kc < 11) ? kc : (490 + kc);
      for (int t = tx; t < 1024; t += 256) {
        int b = t >> 8, i = t & 255;
        s += dst[(size_t)b*HW + i*W + col];
      }
    }
    s = wave_sum(s);
    if (lane == 0) redS[wv] = s;
    __syncthreads();
    if (tx == 0) {
      float tot = redS[0] + redS[1] + redS[2] + redS[3];
      if (k < 22) rowBand[k] = tot; else colBand[k - 22] = tot;
    }
    return;
  }

  int tileId = bid >> 2;       // 512 tiles
  int sub    = bid & 3;
  int half   = sub >> 1;       // 0: db<0, 1: db>0
  int apar   = sub & 1;        // 0: even a, 1: odd a
  int bz = tileId >> 7;        // 128 tiles per batch
  int rem = tileId & 127;
  int i0 = (rem >> 4) * TYR;
  int j0 = (rem & 15) * TX;
  int co = half ? 0 : 11;
  int cbase = j0 - co;         // global col of tile col 0
  bool ceB = (half == 0) && (apar == 0);   // CE once per tile

  const float* lg0 = logit + (size_t)bz*3*HW;
  const float* lg1 = lg0 + HW;
  const float* lg2 = lg0 + 2*HW;
  const float* im0 = image + (size_t)bz*3*HW;
  const float* im1 = im0 + HW;
  const float* im2 = im0 + 2*HW;
  const float* dep = depth + (size_t)bz*HW;
  const float* dsb = dst   + (size_t)bz*HW;
  const int*   tgb = target + (size_t)bz*HW;

  // --- staging: global -> LDS row-pair SoA (phase = apar) with fused softmax; CE on one block/tile ---
  float v0 = 0.f, v1 = 0.f, v2 = 0.f;
  for (int s = tx; s < NP*TCOLS; s += 256) {
    int q = s / TCOLS, c = s - q*TCOLS;
    int gj = cbase + c;
    float fr[2], fg[2], fb[2], fd[2], f0[2], f1[2], f2[2], fm[2];
    #pragma unroll
    for (int hh = 0; hh < 2; ++hh) {
      int r = 2*q - apar + hh;           // tile row of this half
      int gi = i0 + r;
      bool ok = (r >= 0) && (r < TROWS) && (gi < H) && ((unsigned)gj < (unsigned)W);
      if (ok) {
        int qq = gi*W + gj;
        float l0 = lg0[qq], l1 = lg1[qq], l2 = lg2[qq];
        float mx = fmaxf(l0, fmaxf(l1, l2));
        float e0 = __builtin_amdgcn_exp2f((l0-mx)*LOG2E);
        float e1 = __builtin_amdgcn_exp2f((l1-mx)*LOG2E);
        float e2 = __builtin_amdgcn_exp2f((l2-mx)*LOG2E);
        float S = e0+e1+e2;
        float inv = 1.0f/S;
        float m = dsb[qq];
        fr[hh] = im0[qq]*KRGB; fg[hh] = im1[qq]*KRGB;
        fb[hh] = im2[qq]*KRGB; fd[hh] = dep[qq]*KDEP;
        f0[hh] = e0*inv; f1[hh] = e1*inv; f2[hh] = e2*inv; fm[hh] = m;
        if (ceB && r < TYR && c >= co && c < co+TX) {   // center pixel, once per tile
          int t = tgb[qq];
          float lt = (t==0) ? l0 : ((t==1) ? l1 : l2);
          float lce = mx + __logf(S) - lt;
          float t0 = lce * m;
          v0 += t0;
          v1 += lce - t0;
          v2 += m;
        }
      } else {
        fr[hh] = fg[hh] = fb[hh] = fd[hh] = 1e30f;   // +inf sentinel -> kernel = 0
        f0[hh] = f1[hh] = f2[hh] = fm[hh] = 0.f;     // m = 0
      }
    }
    Pk1 p1; p1.rr = pack2(fr[0],fr[1]); p1.gg = pack2(fg[0],fg[1]);
            p1.bb = pack2(fb[0],fb[1]); p1.dd = pack2(fd[0],fd[1]);
    Pk2 p2; p2.y0 = pack2(f0[0],f0[1]); p2.y1 = pack2(f1[0],f1[1]);
            p2.y2 = pack2(f2[0],f2[1]); p2.mm = pack2(fm[0],fm[1]);
    t1[s] = p1; t2[s] = p2;
  }
  __syncthreads();

  if (apar == 0) pairLoop<0>(t1, t2, binsPk, tx, half);
  else           pairLoop<1>(t1, t2, binsPk, tx, half);
  __syncthreads();

  // --- flush bins: 88 lids, each unpacks 4 wave slices in f32 -> 2 global atomics ---
  if (tx < 88) {
    int dbi = tx >> 3, s = tx & 7;
    int NSv = apar ? 6 : 5;
    if (s < NSv) {
      int a  = apar ? (2*s+1) : (2*s+2);
      int db = half ? (dbi+1) : (dbi-11);
      int gid = (a + SPAN)*KK + (db + SPAN);
      float nd = 0.f, nr = 0.f;
      #pragma unroll
      for (int w = 0; w < 4; ++w) {
        h2 v = __builtin_bit_cast(h2, binsPk[w][tx]);
        nd += (float)v.x; nr += (float)v.y;
      }
      if (nd != 0.f) unsafeAtomicAdd(&g_bins[gid], nd);
      if (nr != 0.f) unsafeAtomicAdd(&g_bins[528 - gid], nr);
    }
  }
  if (ceB) {
    v0 = dpp_sum(v0); v1 = dpp_sum(v1); v2 = dpp_sum(v2);
    if (lane == 63) { redS[wv] = v0; redS[4+wv] = v1; redS[8+wv] = v2; }
    __syncthreads();
    if (tx == 0) {
      unsafeAtomicAdd(&g_ce[0], redS[0]+redS[1]+redS[2]+redS[3]);
      unsafeAtomicAdd(&g_ce[1], redS[4]+redS[5]+redS[6]+redS[7]);
      unsafeAtomicAdd(&g_ce[2], redS[8]+redS[9]+redS[10]+redS[11]);
    }
  }
}

// ---------------- fin_kernel: analytic denominators via 2D prefix sum (inclusion-exclusion) ----------------
__global__ __launch_bounds__(256) void fin_kernel(const float* __restrict__ g_bins,
                                                  const float* __restrict__ g_ce,
                                                  const float* __restrict__ rowBand,
                                                  const float* __restrict__ colBand,
                                                  const float* __restrict__ dst,
                                                  float* __restrict__ out) {
  __shared__ float corner[22][22];
  __shared__ float rowp[22][23];     // exclusive row prefixes of corner
  __shared__ float P[23][23];        // exclusive 2D prefix: P[i][j] = sum_{r<i,c<j} corner[r][c]
  __shared__ float rb[22], cb[22];
  __shared__ float TopP[12], BotS[12], LeftP[12], RightS[12];
  __shared__ float red[4];
  int tx = threadIdx.x;
  if (tx < 22) { rb[tx] = rowBand[tx]; cb[tx] = colBand[tx]; }
  for (int t = tx; t < 484; t += 256) {
    int ri = t / 22, ci = t - ri*22;
    int row = (ri < 11) ? ri : (234 + ri);
    int col = (ci < 11) ? ci : (490 + ci);
    float s = 0.f;
    #pragma unroll
    for (int b = 0; b < 4; ++b) s += dst[(size_t)b*HW + row*W + col];
    corner[ri][ci] = s;
  }
  __syncthreads();

  if (tx < 22) {
    float p = 0.f; rowp[tx][0] = 0.f;
    for (int j = 0; j < 22; ++j) { p += corner[tx][j]; rowp[tx][j+1] = p; }
  }
  else if (tx == 32) { float p=0.f; TopP[0]=0.f;   for (int k=1;k<12;++k){ p += rb[k-1];  TopP[k]=p; } }
  else if (tx == 33) { float p=0.f; BotS[0]=0.f;   for (int k=1;k<12;++k){ p += rb[22-k]; BotS[k]=p; } }
  else if (tx == 34) { float p=0.f; LeftP[0]=0.f;  for (int k=1;k<12;++k){ p += cb[k-1];  LeftP[k]=p; } }
  else if (tx == 35) { float p=0.f; RightS[0]=0.f; for (int k=1;k<12;++k){ p += cb[22-k]; RightS[k]=p; } }
  __syncthreads();

  if (tx < 23) {
    float p = 0.f; P[0][tx] = 0.f;
    for (int i = 0; i < 22; ++i) { p += rowp[i][tx]; P[i+1][tx] = p; }
  }
  __syncthreads();

  float S = g_ce[2];   // sum of dst over everything
  float esum = 0.f;
  for (int od = tx; od < NBINS; od += 256) {
    int dxp = od / KK, dyp = od - dxp*KK;
    int dx = dxp - SPAN, dy = dyp - SPAN;
    if (dx != 0 && dy != 0) {
      int ax = (dx < 0) ? -dx : 0;
      int bx = (dx > 0) ?  dx : 0;
      int ay = (dy < 0) ? -dy : 0;
      int by = (dy > 0) ?  dy : 0;
      float TLv = P[ax][ay];
      float TRv = P[ax][22] - P[ax][22-by];
      float BLv = P[22][ay] - P[22-bx][ay];
      float BRv = P[22][22] - P[22-bx][22] - P[22][22-by] + P[22-bx][22-by];
      float den = S - TopP[ax] - BotS[bx] - LeftP[ay] - RightS[by]
                + TLv + TRv + BLv + BRv;
      esum += g_bins[od] / den;
    }
  }
  esum = wave_sum(esum);
  int lane = tx & 63, wv = tx >> 6;
  if (lane == 0) red[wv] = esum;
  __syncthreads();
  if (tx == 0) {
    float E = (red[0]+red[1]+red[2]+red[3]) / 529.0f;
    float count = S / NPIXF;
    float l1 = g_ce[0] / NPIXF;
    float l2 = g_ce[1] / NPIXF;
    out[0] = l1*(1.0f - count) + l2*count;
    out[1] = E;
  }
}

extern "C" void kernel_launch(void* const* d_in, const int* in_sizes, int n_in,
                              void* d_out, int out_size, void* d_ws, size_t ws_size,
                              hipStream_t stream) {
  const float* logit  = (const float*)d_in[0];
  const int*   target = (const int*)  d_in[1];
  const float* image  = (const float*)d_in[2];
  const float* depth  = (const float*)d_in[3];
  const float* dstm   = (const float*)d_in[4];
  float* out = (float*)d_out;

  float* ws      = (float*)d_ws;
  float* g_bins  = ws;             // 529
  float* g_ce    = ws + NBINS;     // 3  (sum lce*m, sum lce*(1-m), sum m)
  float* rowBand = ws + 532;       // 22
  float* colBand = ws + 554;       // 22

  (void)hipMemsetAsync(ws, 0, 532*sizeof(float), stream);
  crf_kernel<<<NCRF + NSTAT, 256, 0, stream>>>(logit, target, image, depth, dstm,
                                               g_bins, g_ce, rowBand, colBand);
  fin_kernel<<<1, 256, 0, stream>>>(g_bins, g_ce, rowBand, colBand, dstm, out);
}

// Round 18
// 162.089 us; speedup vs baseline: 1.1927x; 1.0008x over previous
//
#include <hip/hip_runtime.h>
#include <hip/hip_fp16.h>

#define H 256
#define W 512
#define HW (H*W)
#define NPIXF 524288.0f
#define SPAN 11
#define KK 23
#define NBINS (KK*KK)   // 529

#define LOG2E 1.4426950408889634f
#define CEXP  (-0.7213475204444817f)   // -0.5*log2(e)
#define CIND  (CEXP/36.0f)             // 1/SIG_XY^2
// sqrt(|CEXP|*100) and sqrt(|CEXP|*25): fold rgb/depth sigma scaling into staged f16 data
#define KRGB  8.4932180f
#define KDEP  4.2466090f

// tile geometry: center 32 cols x 32 rows, halo +11 rows below, one-sided 11-col halo.
// LDS is ROW-PAIR packed SoA: pair q covers rows (2q-apar, 2q+1-apar).
#define TX 32
#define TYR 32
#define TROWS 43          // rows 0..42
#define TCOLS 43          // TX + 11 (one-sided halo)
#define NP 22             // row pairs

#define NTILE 512         // 4 batches x 8 rowtiles x 16 coltiles
#define NCRF (NTILE*4)    // 4 blocks per tile: (db half) x (a parity)
#define NSTAT 44

typedef _Float16 h2 __attribute__((ext_vector_type(2)));

struct alignas(16) Pk1 { h2 rr, gg, bb, dd; };   // rgb,d (pre-scaled) for 2 rows
struct alignas(16) Pk2 { h2 y0, y1, y2, mm; };   // softmax probs + mask for 2 rows

__device__ __forceinline__ h2 pack2(float a, float b) {
  h2 r; r.x = (_Float16)a; r.y = (_Float16)b; return r;
}

__device__ __forceinline__ h2 exp2pk(h2 x) {
  __half2 hx = __builtin_bit_cast(__half2, x);
  __half2 hr = h2exp2(hx);
  return __builtin_bit_cast(h2, hr);
}

// build h2(lo = a.hi, hi = b.lo) — phase-1 center assembly (setup only)
__device__ __forceinline__ h2 alignh(h2 a, h2 b) { h2 r; r.x = a.y; r.y = b.x; return r; }
__device__ __forceinline__ Pk1 alignP1(const Pk1& a, const Pk1& b) {
  Pk1 r; r.rr = alignh(a.rr,b.rr); r.gg = alignh(a.gg,b.gg);
  r.bb = alignh(a.bb,b.bb); r.dd = alignh(a.dd,b.dd); return r;
}
__device__ __forceinline__ Pk2 alignP2(const Pk2& a, const Pk2& b) {
  Pk2 r; r.y0 = alignh(a.y0,b.y0); r.y1 = alignh(a.y1,b.y1);
  r.y2 = alignh(a.y2,b.y2); r.mm = alignh(a.mm,b.mm); return r;
}

__device__ __forceinline__ float fdot2f(h2 a, h2 b, float c) {
#if __has_builtin(__builtin_amdgcn_fdot2)
  return __builtin_amdgcn_fdot2(a, b, c, false);
#else
  return c + (float)a.x*(float)b.x + (float)a.y*(float)b.y;
#endif
}

// pack two f32 into packed f16 (one v_cvt_pkrtz_f16_f32).
// NOTE: the builtin returns __fp16 ext_vector_type(2) — bit_cast, don't construct __half2.
__device__ __forceinline__ h2 pkrtz(float a, float b) {
#if __has_builtin(__builtin_amdgcn_cvt_pkrtz)
  auto r = __builtin_amdgcn_cvt_pkrtz(a, b);
  return __builtin_bit_cast(h2, r);
#else
  return pack2(a, b);
#endif
}

// 64-lane sum on the VALU pipe (DPP). Total lands in lane 63.
__device__ __forceinline__ float dpp_sum(float x) {
  x += __int_as_float(__builtin_amdgcn_update_dpp(0, __float_as_int(x), 0x111, 0xf, 0xf, true)); // row_shr:1
  x += __int_as_float(__builtin_amdgcn_update_dpp(0, __float_as_int(x), 0x112, 0xf, 0xf, true)); // row_shr:2
  x += __int_as_float(__builtin_amdgcn_update_dpp(0, __float_as_int(x), 0x114, 0xf, 0xf, true)); // row_shr:4
  x += __int_as_float(__builtin_amdgcn_update_dpp(0, __float_as_int(x), 0x118, 0xf, 0xf, true)); // row_shr:8
  x += __int_as_float(__builtin_amdgcn_update_dpp(0, __float_as_int(x), 0x142, 0xa, 0xf, true)); // row_bcast:15
  x += __int_as_float(__builtin_amdgcn_update_dpp(0, __float_as_int(x), 0x143, 0xc, 0xf, true)); // row_bcast:31
  return x;
}

// packed-f16 64-lane sum (single DPP chain, v_pk_add_f16). Total lands in lane 63.
__device__ __forceinline__ h2 dpp_sum_pk(h2 x) {
  #define STEP(ctl, rmask) x = x + __builtin_bit_cast(h2, __builtin_amdgcn_update_dpp(0, __builtin_bit_cast(int, x), ctl, rmask, 0xf, true));
  STEP(0x111, 0xf)   // row_shr:1
  STEP(0x112, 0xf)   // row_shr:2
  STEP(0x114, 0xf)   // row_shr:4
  STEP(0x118, 0xf)   // row_shr:8
  STEP(0x142, 0xa)   // row_bcast:15
  STEP(0x143, 0xc)   // row_bcast:31
  #undef STEP
  return x;
}

__device__ __forceinline__ float wave_sum(float x) {
  #pragma unroll
  for (int s = 1; s < 64; s <<= 1) x += __shfl_xor(x, s, 64);
  return x;
}

// packed pair compatibility: cc for 2 pairs at once (lo/hi halves)
__device__ __forceinline__ h2 ccpk(const Pk1& C1, const Pk2& C2,
                                   const Pk1& W1, const Pk2& W2, h2 lpk) {
  h2 dr  = W1.rr - C1.rr;
  h2 dg  = W1.gg - C1.gg;
  h2 dbv = W1.bb - C1.bb;
  h2 dd  = W1.dd - C1.dd;
  h2 rs  = dr*dr + dg*dg + dbv*dbv;   // pk fma chain (pre-scaled)
  h2 a1  = lpk - rs;
  h2 a2  = -(dd*dd);
  h2 kv  = exp2pk(a1) + exp2pk(a2);
  h2 one; one.x = (_Float16)1.f; one.y = (_Float16)1.f;
  h2 w   = one - W2.y0*C2.y0 - W2.y1*C2.y1 - W2.y2*C2.y2;
  return kv * w;
}

// main pair loop, a-parity templated (APAR=0: a in {2,4,6,8,10}; APAR=1: a in {1..11 odd}).
// (db,a) wave-sums stored packed (nd,nr) in binsPk[wave][dbi*8+s] — every valid slot written.
// db loop unrolled x2: two independent dataflow chains hide exp/DPP/DS latency.
template<int APAR>
__device__ __forceinline__ void pairLoop(const Pk1* t1, const Pk2* t2,
                                         unsigned (*binsPk)[96], int tx, int half) {
  int lane = tx & 63, wv = tx >> 6;
  int txc = tx & 31, ty = tx >> 5;
  int crow = ty*4;
  int q0 = crow >> 1;
  int co = half ? 0 : 11;
  int ccol = txc + co;

  Pk1 cA1, cB1; Pk2 cA2, cB2;
  if (APAR == 0) {
    cA1 = t1[q0*TCOLS + ccol];      cA2 = t2[q0*TCOLS + ccol];
    cB1 = t1[(q0+1)*TCOLS + ccol];  cB2 = t2[(q0+1)*TCOLS + ccol];
  } else {
    Pk1 pa = t1[q0*TCOLS+ccol], pb = t1[(q0+1)*TCOLS+ccol], pc = t1[(q0+2)*TCOLS+ccol];
    Pk2 qa = t2[q0*TCOLS+ccol], qb = t2[(q0+1)*TCOLS+ccol], qc = t2[(q0+2)*TCOLS+ccol];
    cA1 = alignP1(pa, pb); cB1 = alignP1(pb, pc);
    cA2 = alignP2(qa, qb); cB2 = alignP2(qb, qc);
  }

  int biLo = half * 11;
  #pragma unroll 2
  for (int bi = biLo; bi < biLo + 11; ++bi) {
    int db = bi - ((bi < 11) ? 11 : 10);   // -11..-1 (half 0), 1..11 (half 1)
    int dbi = bi - biLo;                   // 0..10
    int nbcol = ccol + db;                 // stays in [0,42]
    float lb = CIND * (float)(db*db);
    int qw = q0 + 1;                       // first window pair index
    Pk1 wA1 = t1[qw*TCOLS + nbcol];      Pk2 wA2 = t2[qw*TCOLS + nbcol];
    Pk1 wB1 = t1[(qw+1)*TCOLS + nbcol];  Pk2 wB2 = t2[(qw+1)*TCOLS + nbcol];
    constexpr int NS = APAR ? 6 : 5;
    #pragma unroll
    for (int s = 0; s < NS; ++s) {
      if (s > 0) {
        wA1 = wB1; wA2 = wB2;
        wB1 = t1[(qw+s+1)*TCOLS + nbcol]; wB2 = t2[(qw+s+1)*TCOLS + nbcol];
      }
      int a = APAR ? (2*s+1) : (2*s+2);
      float lind = fmaf((float)(a*a), CIND, lb);
      h2 lpk = pack2(lind, lind);
      h2 ccA = ccpk(cA1, cA2, wA1, wA2, lpk);   // pairs: rows (crow,crow+1) vs +a
      h2 ccB = ccpk(cB1, cB2, wB1, wB2, lpk);   // pairs: rows (crow+2,crow+3) vs +a
      float nd = fdot2f(ccA, cA2.mm, 0.f);      // center-m weighted
      nd = fdot2f(ccB, cB2.mm, nd);
      float nr = fdot2f(ccA, wA2.mm, 0.f);      // neighbor-m weighted
      nr = fdot2f(ccB, wB2.mm, nr);
      h2 pk = dpp_sum_pk(pkrtz(nd, nr));        // single packed DPP chain
      if (lane == 63)
        binsPk[wv][dbi*8 + s] = __builtin_bit_cast(unsigned, pk);
    }
  }
}

// ---------------- crf_kernel: row-pair packed f16 SoA tile, 4 center rows/thread,
//                  (db half x a parity) blocks, pk pair math, packed-f16 wave reduction ----------------
__global__ __launch_bounds__(256, 4) void crf_kernel(
    const float* __restrict__ logit, const int* __restrict__ target,
    const float* __restrict__ image, const float* __restrict__ depth,
    const float* __restrict__ dst,
    float* __restrict__ g_bins, float* __restrict__ g_ce,
    float* __restrict__ rowBand, float* __restrict__ colBand) {
  __shared__ Pk1 t1[NP*TCOLS];          // 15.1 KB
  __shared__ Pk2 t2[NP*TCOLS];          // 15.1 KB
  __shared__ unsigned binsPk[4][96];    // 1.5 KB: per-wave packed (nd,nr), lid = dbi*8+s
  __shared__ float redS[12];

  int tx = threadIdx.x;
  int bid = blockIdx.x;
  int lane = tx & 63;
  int wv = tx >> 6;

  if (bid >= NCRF) {           // ---- stats path: margin band sums of dst ----
    int k = bid - NCRF;
    float s = 0.f;
    if (k < 22) {
      int row = (k < 11) ? k : (234 + k);
      for (int t = tx; t < 2048; t += 256) {
        int b = t >> 9, j = t & 511;
        s += dst[(size_t)b*HW + row*W + j];
      }
    } else {
      int kc = k - 22;
      int col = (kc < 11) ? kc : (490 + kc);
      for (int t = tx; t < 1024; t += 256) {
        int b = t >> 8, i = t & 255;
        s += dst[(size_t)b*HW + i*W + col];
      }
    }
    s = wave_sum(s);
    if (lane == 0) redS[wv] = s;
    __syncthreads();
    if (tx == 0) {
      float tot = redS[0] + redS[1] + redS[2] + redS[3];
      if (k < 22) rowBand[k] = tot; else colBand[k - 22] = tot;
    }
    return;
  }

  int tileId = bid >> 2;       // 512 tiles
  int sub    = bid & 3;
  int half   = sub >> 1;       // 0: db<0, 1: db>0
  int apar   = sub & 1;        // 0: even a, 1: odd a
  int bz = tileId >> 7;        // 128 tiles per batch
  int rem = tileId & 127;
  int i0 = (rem >> 4) * TYR;
  int j0 = (rem & 15) * TX;
  int co = half ? 0 : 11;
  int cbase = j0 - co;         // global col of tile col 0
  bool ceB = (half == 0) && (apar == 0);   // CE once per tile

  const float* lg0 = logit + (size_t)bz*3*HW;
  const float* lg1 = lg0 + HW;
  const float* lg2 = lg0 + 2*HW;
  const float* im0 = image + (size_t)bz*3*HW;
  const float* im1 = im0 + HW;
  const float* im2 = im0 + 2*HW;
  const float* dep = depth + (size_t)bz*HW;
  const float* dsb = dst   + (size_t)bz*HW;
  const int*   tgb = target + (size_t)bz*HW;

  // --- staging: global -> LDS row-pair SoA (phase = apar) with fused softmax; CE on one block/tile ---
  float v0 = 0.f, v1 = 0.f, v2 = 0.f;
  for (int s = tx; s < NP*TCOLS; s += 256) {
    int q = s / TCOLS, c = s - q*TCOLS;
    int gj = cbase + c;
    float fr[2], fg[2], fb[2], fd[2], f0[2], f1[2], f2[2], fm[2];
    #pragma unroll
    for (int hh = 0; hh < 2; ++hh) {
      int r = 2*q - apar + hh;           // tile row of this half
      int gi = i0 + r;
      bool ok = (r >= 0) && (r < TROWS) && (gi < H) && ((unsigned)gj < (unsigned)W);
      if (ok) {
        int qq = gi*W + gj;
        float l0 = lg0[qq], l1 = lg1[qq], l2 = lg2[qq];
        float mx = fmaxf(l0, fmaxf(l1, l2));
        float e0 = __builtin_amdgcn_exp2f((l0-mx)*LOG2E);
        float e1 = __builtin_amdgcn_exp2f((l1-mx)*LOG2E);
        float e2 = __builtin_amdgcn_exp2f((l2-mx)*LOG2E);
        float S = e0+e1+e2;
        float inv = 1.0f/S;
        float m = dsb[qq];
        fr[hh] = im0[qq]*KRGB; fg[hh] = im1[qq]*KRGB;
        fb[hh] = im2[qq]*KRGB; fd[hh] = dep[qq]*KDEP;
        f0[hh] = e0*inv; f1[hh] = e1*inv; f2[hh] = e2*inv; fm[hh] = m;
        if (ceB && r < TYR && c >= co && c < co+TX) {   // center pixel, once per tile
          int t = tgb[qq];
          float lt = (t==0) ? l0 : ((t==1) ? l1 : l2);
          float lce = mx + __logf(S) - lt;
          float t0 = lce * m;
          v0 += t0;
          v1 += lce - t0;
          v2 += m;
        }
      } else {
        fr[hh] = fg[hh] = fb[hh] = fd[hh] = 1e30f;   // +inf sentinel -> kernel = 0
        f0[hh] = f1[hh] = f2[hh] = fm[hh] = 0.f;     // m = 0
      }
    }
    Pk1 p1; p1.rr = pack2(fr[0],fr[1]); p1.gg = pack2(fg[0],fg[1]);
            p1.bb = pack2(fb[0],fb[1]); p1.dd = pack2(fd[0],fd[1]);
    Pk2 p2; p2.y0 = pack2(f0[0],f0[1]); p2.y1 = pack2(f1[0],f1[1]);
            p2.y2 = pack2(f2[0],f2[1]); p2.mm = pack2(fm[0],fm[1]);
    t1[s] = p1; t2[s] = p2;
  }
  __syncthreads();

  if (apar == 0) pairLoop<0>(t1, t2, binsPk, tx, half);
  else           pairLoop<1>(t1, t2, binsPk, tx, half);
  __syncthreads();

  // --- flush bins: 88 lids, each unpacks 4 wave slices in f32 -> 2 global atomics ---
  if (tx < 88) {
    int dbi = tx >> 3, s = tx & 7;
    int NSv = apar ? 6 : 5;
    if (s < NSv) {
      int a  = apar ? (2*s+1) : (2*s+2);
      int db = half ? (dbi+1) : (dbi-11);
      int gid = (a + SPAN)*KK + (db + SPAN);
      float nd = 0.f, nr = 0.f;
      #pragma unroll
      for (int w = 0; w < 4; ++w) {
        h2 v = __builtin_bit_cast(h2, binsPk[w][tx]);
        nd += (float)v.x; nr += (float)v.y;
      }
      if (nd != 0.f) unsafeAtomicAdd(&g_bins[gid], nd);
      if (nr != 0.f) unsafeAtomicAdd(&g_bins[528 - gid], nr);
    }
  }
  if (ceB) {
    v0 = dpp_sum(v0); v1 = dpp_sum(v1); v2 = dpp_sum(v2);
    if (lane == 63) { redS[wv] = v0; redS[4+wv] = v1; redS[8+wv] = v2; }
    __syncthreads();
    if (tx == 0) {
      unsafeAtomicAdd(&g_ce[0], redS[0]+redS[1]+redS[2]+redS[3]);
      unsafeAtomicAdd(&g_ce[1], redS[4]+redS[5]+redS[6]+redS[7]);
      unsafeAtomicAdd(&g_ce[2], redS[8]+redS[9]+redS[10]+redS[11]);
    }
  }
}

// ---------------- fin_kernel: analytic denominators via 2D prefix sum (inclusion-exclusion) ----------------
__global__ __launch_bounds__(256) void fin_kernel(const float* __restrict__ g_bins,
                                                  const float* __restrict__ g_ce,
                                                  const float* __restrict__ rowBand,
                                                  const float* __restrict__ colBand,
                                                  const float* __restrict__ dst,
                                                  float* __restrict__ out) {
  __shared__ float corner[22][22];
  __shared__ float rowp[22][23];     // exclusive row prefixes of corner
  __shared__ float P[23][23];        // exclusive 2D prefix: P[i][j] = sum_{r<i,c<j} corner[r][c]
  __shared__ float rb[22], cb[22];
  __shared__ float TopP[12], BotS[12], LeftP[12], RightS[12];
  __shared__ float red[4];
  int tx = threadIdx.x;
  if (tx < 22) { rb[tx] = rowBand[tx]; cb[tx] = colBand[tx]; }
  for (int t = tx; t < 484; t += 256) {
    int ri = t / 22, ci = t - ri*22;
    int row = (ri < 11) ? ri : (234 + ri);
    int col = (ci < 11) ? ci : (490 + ci);
    float s = 0.f;
    #pragma unroll
    for (int b = 0; b < 4; ++b) s += dst[(size_t)b*HW + row*W + col];
    corner[ri][ci] = s;
  }
  __syncthreads();

  if (tx < 22) {
    float p = 0.f; rowp[tx][0] = 0.f;
    for (int j = 0; j < 22; ++j) { p += corner[tx][j]; rowp[tx][j+1] = p; }
  }
  else if (tx == 32) { float p=0.f; TopP[0]=0.f;   for (int k=1;k<12;++k){ p += rb[k-1];  TopP[k]=p; } }
  else if (tx == 33) { float p=0.f; BotS[0]=0.f;   for (int k=1;k<12;++k){ p += rb[22-k]; BotS[k]=p; } }
  else if (tx == 34) { float p=0.f; LeftP[0]=0.f;  for (int k=1;k<12;++k){ p += cb[k-1];  LeftP[k]=p; } }
  else if (tx == 35) { float p=0.f; RightS[0]=0.f; for (int k=1;k<12;++k){ p += cb[22-k]; RightS[k]=p; } }
  __syncthreads();

  if (tx < 23) {
    float p = 0.f; P[0][tx] = 0.f;
    for (int i = 0; i < 22; ++i) { p += rowp[i][tx]; P[i+1][tx] = p; }
  }
  __syncthreads();

  float S = g_ce[2];   // sum of dst over everything
  float esum = 0.f;
  for (int od = tx; od < NBINS; od += 256) {
    int dxp = od / KK, dyp = od - dxp*KK;
    int dx = dxp - SPAN, dy = dyp - SPAN;
    if (dx != 0 && dy != 0) {
      int ax = (dx < 0) ? -dx : 0;
      int bx = (dx > 0) ?  dx : 0;
      int ay = (dy < 0) ? -dy : 0;
      int by = (dy > 0) ?  dy : 0;
      float TLv = P[ax][ay];
      float TRv = P[ax][22] - P[ax][22-by];
      float BLv = P[22][ay] - P[22-bx][ay];
      float BRv = P[22][22] - P[22-bx][22] - P[22][22-by] + P[22-bx][22-by];
      float den = S - TopP[ax] - BotS[bx] - LeftP[ay] - RightS[by]
                + TLv + TRv + BLv + BRv;
      esum += g_bins[od] / den;
    }
  }
  esum = wave_sum(esum);
  int lane = tx & 63, wv = tx >> 6;
  if (lane == 0) red[wv] = esum;
  __syncthreads();
  if (tx == 0) {
    float E = (red[0]+red[1]+red[2]+red[3]) / 529.0f;
    float count = S / NPIXF;
    float l1 = g_ce[0] / NPIXF;
    float l2 = g_ce[1] / NPIXF;
    out[0] = l1*(1.0f - count) + l2*count;
    out[1] = E;
  }
}

extern "C" void kernel_launch(void* const* d_in, const int* in_sizes, int n_in,
                              void* d_out, int out_size, void* d_ws, size_t ws_size,
                              hipStream_t stream) {
  const float* logit  = (const float*)d_in[0];
  const int*   target = (const int*)  d_in[1];
  const float* image  = (const float*)d_in[2];
  const float* depth  = (const float*)d_in[3];
  const float* dstm   = (const float*)d_in[4];
  float* out = (float*)d_out;

  float* ws      = (float*)d_ws;
  float* g_bins  = ws;             // 529
  float* g_ce    = ws + NBINS;     // 3  (sum lce*m, sum lce*(1-m), sum m)
  float* rowBand = ws + 532;       // 22
  float* colBand = ws + 554;       // 22

  (void)hipMemsetAsync(ws, 0, 532*sizeof(float), stream);
  crf_kernel<<<NCRF + NSTAT, 256, 0, stream>>>(logit, target, image, depth, dstm,
                                               g_bins, g_ce, rowBand, colBand);
  fin_kernel<<<1, 256, 0, stream>>>(g_bins, g_ce, rowBand, colBand, dstm, out);
}